// Round 11
// baseline (197.430 us; speedup 1.0000x reference)
//
#include <hip/hip_runtime.h>
#include <hip/hip_bf16.h>
#include <cstddef>

#define G_   2048
#define NPG_ 512
#define CPG_ 128
#define CPG2_ 32

// output layout (floats): z_what[G,64] | z_mask[G,64] | mu[G,128] | sigma[G,128] | f[G,256]
#define OFF_ZW 0
#define OFF_ZM (G_*64)
#define OFF_MU (2*G_*64)
#define OFF_SG (2*G_*64 + G_*128)
#define OFF_F  (2*G_*64 + 2*G_*128)

typedef __attribute__((ext_vector_type(8))) short bf16x8;
typedef __attribute__((ext_vector_type(4))) float f32x4;

__device__ __forceinline__ float celu_f(float x)     { return x > 0.f ? x : __expf(x) - 1.f; }
__device__ __forceinline__ float softplus_f(float x) { return fmaxf(x, 0.f) + __logf(1.f + __expf(-fabsf(x))); }
__device__ __forceinline__ unsigned short f2bf(float x) {
    __hip_bfloat16 h = __float2bfloat16(x);
    return *reinterpret_cast<unsigned short*>(&h);
}

// ---------------- prep: transposed, zero-K-padded bf16 weight copies in ws ----------------
__global__ void k_prep(const float* __restrict__ W2l, const float* __restrict__ W2g,
                       const float* __restrict__ W3l, const float* __restrict__ W3g,
                       const float* __restrict__ Wlin,
                       unsigned short* __restrict__ w2lT, unsigned short* __restrict__ w2gT,
                       unsigned short* __restrict__ w3lT, unsigned short* __restrict__ w3gT,
                       unsigned short* __restrict__ wlinT)
{
    const int tid = blockIdx.x*256 + threadIdx.x, stride = gridDim.x*256;
    for (int i = tid; i < 64*64; i += stride) {          // W2l [35,64] -> [ch][k=64pad]
        const int ch = i >> 6, k = i & 63;
        w2lT[i] = f2bf(k < 35 ? W2l[k*64 + ch] : 0.f);
    }
    for (int i = tid; i < 128*64; i += stride) {         // W2g [64,128] -> [ch][k]
        const int ch = i >> 6, k = i & 63;
        w2gT[i] = f2bf(W2g[k*128 + ch]);
    }
    for (int i = tid; i < 128*160; i += stride) {        // W3l [131,128] -> [ch][k=160pad]
        const int ch = i / 160, k = i % 160;
        w3lT[i] = f2bf(k < 131 ? W3l[k*128 + ch] : 0.f);
    }
    for (int i = tid; i < 256*128; i += stride) {        // W3g [128,256] -> [ch][k]
        const int ch = i >> 7, k = i & 127;
        w3gT[i] = f2bf(W3g[k*256 + ch]);
    }
    for (int i = tid; i < 256*256; i += stride) {        // Wlin [256,256] -> [ch][k]
        const int ch = i >> 8, k = i & 255;
        wlinT[i] = f2bf(Wlin[k*256 + ch]);
    }
}

// ============== fused pipeline: one block per glimpse ==============
// LDS map (44800 B total, phase overlays):
//  RegA  [0,10240):   pts SoA + order (conv1 A-D) -> sT (conv2) -> agg2 -> red+aggB (conv3)
//  RegB  [10240,22528): aggT+sW1g (conv1) -> xs3 (conv2 out / conv3 in) -> f3B
//  xs16  [22528,40960): conv2 A-matrix (f1+relpos) -> HT
//  ints  [40960,43008): cnt/start/ctr/scan
//  slc   [43008,43520); cnti [43520,43648); invc [43648,43776); outs [43776,44800)
__global__ __launch_bounds__(256, 3) void k_fused(
    const float* __restrict__ rgb, const float* __restrict__ pos, const float* __restrict__ pos1,
    const float* __restrict__ pos2, const int* __restrict__ idx0, const int* __restrict__ idx1,
    const float* __restrict__ eps,
    const float* __restrict__ W1l, const float* __restrict__ b1l,
    const float* __restrict__ W1g, const float* __restrict__ b1g,
    const unsigned short* __restrict__ w2lT, const float* __restrict__ b2l,
    const unsigned short* __restrict__ w2gT, const float* __restrict__ b2g,
    const unsigned short* __restrict__ w3lT, const float* __restrict__ b3l,
    const unsigned short* __restrict__ w3gT, const float* __restrict__ b3g,
    const unsigned short* __restrict__ wlinT, const float* __restrict__ blin,
    float* __restrict__ out)
{
    const int g = blockIdx.x, t = threadIdx.x;
    const int lane = t & 63, wv = t >> 6;
    const int lr = lane & 15, quad = lane >> 4;

    __shared__ __align__(16) unsigned char smem[44800];
    float* const sx0 = (float*)(smem);
    float* const srx = sx0 + 512;
    float* const sry = srx + 512;
    float* const srz = sry + 512;
    unsigned short* const slc1  = (unsigned short*)(smem + 8192);
    unsigned short* const order = slc1 + 512;
    unsigned short* const sT    = (unsigned short*)smem;           // [32][136]
    unsigned short* const agg2  = (unsigned short*)smem;           // [32][72]
    float* const red  = (float*)smem;                              // [128][9]
    unsigned short* const aggB = (unsigned short*)(smem + 4608);   // [16][136]
    float* const aggT = (float*)(smem + 10240);                    // [128][20]
    float* const sW1g = (float*)(smem + 20480);                    // [512]
    unsigned short* const xs3  = (unsigned short*)(smem + 10240);  // [32][168]
    unsigned short* const f3B  = (unsigned short*)(smem + 10240);  // [16][264]
    unsigned short* const xs16 = (unsigned short*)(smem + 22528);  // [128][72]
    unsigned short* const HT   = xs16;                             // [64][136]
    int* const cnt   = (int*)(smem + 40960);
    int* const start = cnt + 128;
    int* const ctr   = start + 128;
    int* const scan  = ctr + 128;
    int* const slc   = (int*)(smem + 43008);
    int* const cnti  = (int*)(smem + 43520);
    float* const invc = (float*)(smem + 43648);
    float* const outs = (float*)(smem + 43776);                    // [256]

    // ---- early setup (pre-B0): slc, relpos into xs16, zero-pad xs16, counters ----
    for (int i = t; i < 512; i += 256) sW1g[i] = W1g[i];
    if (t < CPG_) cnt[t] = 0;
    if (t < CPG2_) cnti[t] = 0;
    if (t < CPG_) {
        const int c2 = idx1[g*CPG_ + t];
        slc[t] = c2 - g*CPG2_;
        #pragma unroll
        for (int d = 0; d < 3; d++)
            xs16[t*72 + 32 + d] = f2bf(pos1[(g*CPG_ + t)*3 + d] - pos2[c2*3 + d]);
    }
    for (int i = t; i < 128*29; i += 256) {     // zero xs16 cols 35..63
        const int r = i / 29, c = 35 + (i - r*29);
        xs16[r*72 + c] = 0;
    }
    __syncthreads();   // B0

    // ---- conv1 Phase A: stage points + counts ----
    #pragma unroll
    for (int r = 0; r < 2; r++) {
        const int lp = r*256 + t;
        const int p  = g*NPG_ + lp;
        const int c  = idx0[p];
        const int lc = c - g*CPG_;
        sx0[lp] = rgb[p];
        srx[lp] = pos[p*3+0] - pos1[c*3+0];
        sry[lp] = pos[p*3+1] - pos1[c*3+1];
        srz[lp] = pos[p*3+2] - pos1[c*3+2];
        slc1[lp] = (unsigned short)lc;
        atomicAdd(&cnt[lc], 1);
    }
    if (t < CPG_) atomicAdd(&cnti[slc[t]], 1);
    __syncthreads();   // B1

    // ---- Phase B: wave scan over cnt[128] ----
    if (t < CPG_) {
        int val = cnt[t];
        const int ln = t & 63;
        #pragma unroll
        for (int d = 1; d < 64; d <<= 1) {
            const int v = __shfl_up(val, d, 64);
            if (ln >= d) val += v;
        }
        scan[t] = val;
    }
    __syncthreads();   // B2
    if (t >= 64 && t < CPG_) scan[t] += scan[63];
    __syncthreads();   // B3
    if (t < CPG_) { const int s = scan[t] - cnt[t]; start[t] = s; ctr[t] = s; }
    if (t < CPG2_) invc[t] = 1.f / fmaxf((float)cnti[t], 1.f);
    __syncthreads();   // B4

    // ---- Phase C: scatter point ids ----
    #pragma unroll
    for (int r = 0; r < 2; r++) {
        const int lp = r*256 + t;
        const int slot = atomicAdd(&ctr[slc1[lp]], 1);
        order[slot] = (unsigned short)lp;
    }
    __syncthreads();   // B5

    // ---- Phase D: accumulate per cluster (2 threads/cluster) -> aggT ----
    {
        const int c = t >> 1, ch0 = (t & 1) * 8;
        float wj[8], wx[8], wy[8], wz[8], bb2[8];
        #pragma unroll
        for (int j = 0; j < 8; j++) {
            wj[j] = W1l[ch0+j]; wx[j] = W1l[16+ch0+j];
            wy[j] = W1l[32+ch0+j]; wz[j] = W1l[48+ch0+j];
            bb2[j] = b1l[ch0+j];
        }
        float a[8];
        #pragma unroll
        for (int j = 0; j < 8; j++) a[j] = 0.f;
        const int n = cnt[c], base = start[c];
        for (int i = 0; i < n; i++) {
            const int lp = order[base + i];
            const float x0 = sx0[lp], rx = srx[lp], ry = sry[lp], rz = srz[lp];
            #pragma unroll
            for (int j = 0; j < 8; j++) {
                const float h = bb2[j] + x0*wj[j] + rx*wx[j] + ry*wy[j] + rz*wz[j];
                a[j] += celu_f(h);
            }
        }
        const float inv = 1.f / fmaxf((float)n, 1.f);
        #pragma unroll
        for (int j = 0; j < 8; j++) aggT[c*20 + ch0 + j] = a[j] * inv;
    }
    __syncthreads();   // B6  (RegA pts dead; sT region free)

    // ---- conv1 global conv -> f1 bf16 straight into xs16 cols 0..31; build sT one-hot ----
    {
        const int oc = t & 31;
        float wreg[16];
        #pragma unroll
        for (int j = 0; j < 16; j++) wreg[j] = sW1g[j*32 + oc];
        const float bg = b1g[oc];
        #pragma unroll
        for (int i = 0; i < 16; i++) {
            const int lc = (t >> 5) + i*8;
            float a = bg;
            #pragma unroll
            for (int j = 0; j < 16; j += 4) {
                const float4 a4 = *(const float4*)&aggT[lc*20 + j];
                a += a4.x*wreg[j] + a4.y*wreg[j+1] + a4.z*wreg[j+2] + a4.w*wreg[j+3];
            }
            xs16[lc*72 + oc] = f2bf(celu_f(a));
        }
    }
    for (int i = t; i < 1088; i += 256) ((uint2*)sT)[i] = make_uint2(0u, 0u);
    __syncthreads();   // B6b (sT zeroed before scatter; aggT reads done)
    if (t < CPG_) sT[slc[t]*136 + t] = 0x3F80;   // bf16 1.0
    __syncthreads();   // B7

    // ---- conv2 P1: local conv MFMA ----
    float hv[8][4];
    {
        const int chn = wv*16 + lr;
        const bf16x8 bw0 = *(const bf16x8*)&w2lT[chn*64 + quad*8];
        const bf16x8 bw1 = *(const bf16x8*)&w2lT[chn*64 + 32 + quad*8];
        const float bias = b2l[chn];
        #pragma unroll
        for (int m = 0; m < 8; m++) {
            f32x4 acc = (f32x4){bias, bias, bias, bias};
            const bf16x8 a0 = *(const bf16x8*)&xs16[(m*16 + lr)*72 + quad*8];
            const bf16x8 a1 = *(const bf16x8*)&xs16[(m*16 + lr)*72 + 32 + quad*8];
            acc = __builtin_amdgcn_mfma_f32_16x16x32_bf16(a0, bw0, acc, 0, 0, 0);
            acc = __builtin_amdgcn_mfma_f32_16x16x32_bf16(a1, bw1, acc, 0, 0, 0);
            #pragma unroll
            for (int r = 0; r < 4; r++) hv[m][r] = celu_f(acc[r]);
        }
    }
    __syncthreads();   // B8  (xs16 dead -> HT; RegB aggT/sW1g dead -> xs3)

    // ---- conv2 P2: store H^T; prep xs3 pads ----
    {
        const int chn = wv*16 + lr;
        #pragma unroll
        for (int m = 0; m < 8; m++) {
            uint2 p;
            p.x = (unsigned)f2bf(hv[m][0]) | ((unsigned)f2bf(hv[m][1]) << 16);
            p.y = (unsigned)f2bf(hv[m][2]) | ((unsigned)f2bf(hv[m][3]) << 16);
            *(uint2*)&HT[chn*136 + m*16 + quad*4] = p;
        }
    }
    if (t < CPG2_) {
        #pragma unroll
        for (int d = 0; d < 3; d++)
            xs3[t*168 + 128 + d] = f2bf(pos2[(g*CPG2_ + t)*3 + d]);
    }
    for (int i = t; i < 32*29; i += 256) {     // zero xs3 cols 131..159
        const int r = i / 29, c = 131 + (i - r*29);
        xs3[r*168 + c] = 0;
    }
    __syncthreads();   // B9

    // ---- conv2 P3: segment-sum MFMA agg[32][64] = S^T @ H ----
    float aggv[2][4];
    {
        const int ch = wv*16 + lr;
        f32x4 acc[2];
        acc[0] = (f32x4){0.f, 0.f, 0.f, 0.f};
        acc[1] = (f32x4){0.f, 0.f, 0.f, 0.f};
        #pragma unroll
        for (int ks = 0; ks < 4; ks++) {
            const bf16x8 b = *(const bf16x8*)&HT[ch*136 + ks*32 + quad*8];
            #pragma unroll
            for (int mt = 0; mt < 2; mt++) {
                const bf16x8 a = *(const bf16x8*)&sT[(mt*16 + lr)*136 + ks*32 + quad*8];
                acc[mt] = __builtin_amdgcn_mfma_f32_16x16x32_bf16(a, b, acc[mt], 0, 0, 0);
            }
        }
        #pragma unroll
        for (int mt = 0; mt < 2; mt++)
        #pragma unroll
        for (int r = 0; r < 4; r++)
            aggv[mt][r] = acc[mt][r] * invc[mt*16 + quad*4 + r];
    }
    __syncthreads();   // B10 (sT dead -> agg2)

    // ---- conv2 P4: store agg bf16 ----
    {
        const int ch = wv*16 + lr;
        #pragma unroll
        for (int mt = 0; mt < 2; mt++)
        #pragma unroll
        for (int r = 0; r < 4; r++)
            agg2[(mt*16 + quad*4 + r)*72 + ch] = f2bf(aggv[mt][r]);
    }
    __syncthreads();   // B11

    // ---- conv2 P5: global conv MFMA -> f2 bf16 straight into xs3 cols 0..127 ----
    {
        f32x4 acc2[2][2];
        int   chn2[2];
        bf16x8 bw[2][2];
        #pragma unroll
        for (int nt = 0; nt < 2; nt++) {
            chn2[nt] = (wv + nt*4)*16 + lr;
            const float bias = b2g[chn2[nt]];
            #pragma unroll
            for (int mt = 0; mt < 2; mt++) acc2[nt][mt] = (f32x4){bias, bias, bias, bias};
            bw[nt][0] = *(const bf16x8*)&w2gT[chn2[nt]*64 + quad*8];
            bw[nt][1] = *(const bf16x8*)&w2gT[chn2[nt]*64 + 32 + quad*8];
        }
        #pragma unroll
        for (int ks = 0; ks < 2; ks++) {
            #pragma unroll
            for (int mt = 0; mt < 2; mt++) {
                const bf16x8 a = *(const bf16x8*)&agg2[(mt*16 + lr)*72 + ks*32 + quad*8];
                acc2[0][mt] = __builtin_amdgcn_mfma_f32_16x16x32_bf16(a, bw[0][ks], acc2[0][mt], 0, 0, 0);
                acc2[1][mt] = __builtin_amdgcn_mfma_f32_16x16x32_bf16(a, bw[1][ks], acc2[1][mt], 0, 0, 0);
            }
        }
        #pragma unroll
        for (int nt = 0; nt < 2; nt++)
        #pragma unroll
        for (int mt = 0; mt < 2; mt++)
        #pragma unroll
        for (int r = 0; r < 4; r++) {
            const int row = mt*16 + quad*4 + r;
            xs3[row*168 + chn2[nt]] = f2bf(celu_f(acc2[nt][mt][r]));
        }
    }
    __syncthreads();   // B12 (agg2 dead -> red/aggB)

    // ---- conv3 local conv MFMA (M=32) -> celu -> partials into red; zero aggB ----
    for (int i = t; i < 1088; i += 256) ((unsigned*)aggB)[i] = 0u;
    {
        f32x4 acc[2][2];
        int chn[2];
        #pragma unroll
        for (int nt = 0; nt < 2; nt++) {
            chn[nt] = (wv + nt*4)*16 + lr;
            const float bias = b3l[chn[nt]];
            #pragma unroll
            for (int mt = 0; mt < 2; mt++) acc[nt][mt] = (f32x4){bias, bias, bias, bias};
        }
        #pragma unroll
        for (int ks = 0; ks < 5; ks++) {
            const bf16x8 b0 = *(const bf16x8*)&w3lT[chn[0]*160 + ks*32 + quad*8];
            const bf16x8 b1 = *(const bf16x8*)&w3lT[chn[1]*160 + ks*32 + quad*8];
            #pragma unroll
            for (int mt = 0; mt < 2; mt++) {
                const bf16x8 a = *(const bf16x8*)&xs3[(mt*16 + lr)*168 + ks*32 + quad*8];
                acc[0][mt] = __builtin_amdgcn_mfma_f32_16x16x32_bf16(a, b0, acc[0][mt], 0, 0, 0);
                acc[1][mt] = __builtin_amdgcn_mfma_f32_16x16x32_bf16(a, b1, acc[1][mt], 0, 0, 0);
            }
        }
        #pragma unroll
        for (int nt = 0; nt < 2; nt++)
        #pragma unroll
        for (int mt = 0; mt < 2; mt++) {
            const float p = celu_f(acc[nt][mt][0]) + celu_f(acc[nt][mt][1])
                          + celu_f(acc[nt][mt][2]) + celu_f(acc[nt][mt][3]);
            red[chn[nt]*9 + mt*4 + quad] = p;
        }
    }
    __syncthreads();   // B13 (xs3 reads done -> f3B)

    // ---- mean reduce -> aggB row 0; zero f3B rows 1..15 ----
    if (t < 128) {
        const float* rp = &red[t*9];
        float a = 0.f;
        #pragma unroll
        for (int p = 0; p < 8; p++) a += rp[p];
        aggB[t] = f2bf(a * (1.f/32.f));
    }
    for (int i = t; i < 15*264; i += 256) f3B[264 + i] = 0;
    __syncthreads();   // B14

    // ---- W3g MFMA (M=16 pad, row 0 valid) -> f3 -> out F + f3B row 0 ----
    {
        f32x4 c3[4];
        int ch3[4];
        #pragma unroll
        for (int nt = 0; nt < 4; nt++) {
            ch3[nt] = (wv + nt*4)*16 + lr;
            const float bias = b3g[ch3[nt]];
            c3[nt] = (f32x4){bias, bias, bias, bias};
        }
        #pragma unroll
        for (int ks = 0; ks < 4; ks++) {
            const bf16x8 a = *(const bf16x8*)&aggB[lr*136 + ks*32 + quad*8];
            #pragma unroll
            for (int nt = 0; nt < 4; nt++) {
                const bf16x8 b = *(const bf16x8*)&w3gT[ch3[nt]*128 + ks*32 + quad*8];
                c3[nt] = __builtin_amdgcn_mfma_f32_16x16x32_bf16(a, b, c3[nt], 0, 0, 0);
            }
        }
        if (quad == 0) {
            #pragma unroll
            for (int nt = 0; nt < 4; nt++) {
                const float v = celu_f(c3[nt][0]);   // C row 0 = glimpse
                out[OFF_F + (size_t)g*256 + ch3[nt]] = v;
                f3B[ch3[nt]] = f2bf(v);
            }
        }
    }
    __syncthreads();   // B15

    // ---- Wlin MFMA -> outs ----
    {
        f32x4 cl[4];
        int ch4[4];
        #pragma unroll
        for (int nt = 0; nt < 4; nt++) {
            ch4[nt] = (wv + nt*4)*16 + lr;
            const float bias = blin[ch4[nt]];
            cl[nt] = (f32x4){bias, bias, bias, bias};
        }
        #pragma unroll
        for (int ks = 0; ks < 8; ks++) {
            const bf16x8 a = *(const bf16x8*)&f3B[lr*264 + ks*32 + quad*8];
            #pragma unroll
            for (int nt = 0; nt < 4; nt++) {
                const bf16x8 b = *(const bf16x8*)&wlinT[ch4[nt]*256 + ks*32 + quad*8];
                cl[nt] = __builtin_amdgcn_mfma_f32_16x16x32_bf16(a, b, cl[nt], 0, 0, 0);
            }
        }
        if (quad == 0) {
            #pragma unroll
            for (int nt = 0; nt < 4; nt++) outs[ch4[nt]] = cl[nt][0];
        }
    }
    __syncthreads();   // B16

    // ---- sample ----
    if (t < 128) {
        const float mu    = outs[t];
        const float sigma = softplus_f(outs[128 + t]);
        const float z     = mu + sigma * eps[g*128 + t];
        out[OFF_MU + g*128 + t] = mu;
        out[OFF_SG + g*128 + t] = sigma;
        if (t < 64) out[OFF_ZW + g*64 + t] = z;
        else        out[OFF_ZM + g*64 + (t - 64)] = z;
    }
}

extern "C" void kernel_launch(void* const* d_in, const int* in_sizes, int n_in,
                              void* d_out, int out_size, void* d_ws, size_t ws_size,
                              hipStream_t stream)
{
    const float* rgb  = (const float*)d_in[0];
    const float* pos  = (const float*)d_in[1];
    const float* pos1 = (const float*)d_in[2];
    const float* pos2 = (const float*)d_in[3];
    const int*   idx0 = (const int*)d_in[4];
    const int*   idx1 = (const int*)d_in[5];
    const float* eps  = (const float*)d_in[7];
    const float* W1l = (const float*)d_in[8],  *b1l = (const float*)d_in[9];
    const float* W1g = (const float*)d_in[10], *b1g = (const float*)d_in[11];
    const float* W2l = (const float*)d_in[12], *b2l = (const float*)d_in[13];
    const float* W2g = (const float*)d_in[14], *b2g = (const float*)d_in[15];
    const float* W3l = (const float*)d_in[16], *b3l = (const float*)d_in[17];
    const float* W3g = (const float*)d_in[18], *b3g = (const float*)d_in[19];
    const float* Wlin = (const float*)d_in[20], *blin = (const float*)d_in[21];

    unsigned short* w2lT  = (unsigned short*)d_ws;       // 64*64
    unsigned short* w2gT  = w2lT + 64*64;                // 128*64
    unsigned short* w3lT  = w2gT + 128*64;               // 128*160
    unsigned short* w3gT  = w3lT + 128*160;              // 256*128
    unsigned short* wlinT = w3gT + 256*128;              // 256*256
    float* outp = (float*)d_out;

    k_prep <<<64, 256, 0, stream>>>(W2l, W2g, W3l, W3g, Wlin, w2lT, w2gT, w3lT, w3gT, wlinT);
    k_fused<<<G_, 256, 0, stream>>>(rgb, pos, pos1, pos2, idx0, idx1, eps,
                                    W1l, b1l, W1g, b1g,
                                    w2lT, b2l, w2gT, b2g, w3lT, b3l, w3gT, b3g, wlinT, blin,
                                    outp);
}

// Round 12
// 161.319 us; speedup vs baseline: 1.2239x; 1.2239x over previous
//
#include <hip/hip_runtime.h>
#include <hip/hip_bf16.h>
#include <cstddef>

#define G_   2048
#define NPG_ 512
#define CPG_ 128
#define CPG2_ 32

// output layout (floats): z_what[G,64] | z_mask[G,64] | mu[G,128] | sigma[G,128] | f[G,256]
#define OFF_ZW 0
#define OFF_ZM (G_*64)
#define OFF_MU (2*G_*64)
#define OFF_SG (2*G_*64 + G_*128)
#define OFF_F  (2*G_*64 + 2*G_*128)

typedef __attribute__((ext_vector_type(8))) short bf16x8;
typedef __attribute__((ext_vector_type(4))) float f32x4;

__device__ __forceinline__ float celu_f(float x)     { return x > 0.f ? x : __expf(x) - 1.f; }
__device__ __forceinline__ float softplus_f(float x) { return fmaxf(x, 0.f) + __logf(1.f + __expf(-fabsf(x))); }
__device__ __forceinline__ unsigned short f2bf(float x) {
    __hip_bfloat16 h = __float2bfloat16(x);
    return *reinterpret_cast<unsigned short*>(&h);
}
__device__ __forceinline__ float bflo(unsigned w) { return __uint_as_float(w << 16); }
__device__ __forceinline__ float bfhi(unsigned w) { return __uint_as_float(w & 0xffff0000u); }

// ---------------- prep: transposed, zero-K-padded bf16 weight copies in ws ----------------
__global__ void k_prep(const float* __restrict__ W2l, const float* __restrict__ W2g,
                       const float* __restrict__ W3l, const float* __restrict__ W3g,
                       const float* __restrict__ Wlin,
                       unsigned short* __restrict__ w2lT, unsigned short* __restrict__ w2gT,
                       unsigned short* __restrict__ w3lT, unsigned short* __restrict__ w3gT,
                       unsigned short* __restrict__ wlinT)
{
    const int tid = blockIdx.x*256 + threadIdx.x, stride = gridDim.x*256;
    for (int i = tid; i < 64*64; i += stride) {          // W2l [35,64] -> [ch][k=64pad]
        const int ch = i >> 6, k = i & 63;
        w2lT[i] = f2bf(k < 35 ? W2l[k*64 + ch] : 0.f);
    }
    for (int i = tid; i < 128*64; i += stride) {         // W2g [64,128] -> [ch][k]
        const int ch = i >> 6, k = i & 63;
        w2gT[i] = f2bf(W2g[k*128 + ch]);
    }
    for (int i = tid; i < 128*160; i += stride) {        // W3l [131,128] -> [ch][k=160pad]
        const int ch = i / 160, k = i % 160;
        w3lT[i] = f2bf(k < 131 ? W3l[k*128 + ch] : 0.f);
    }
    for (int i = tid; i < 256*128; i += stride) {        // W3g [128,256] -> [ch][k]
        const int ch = i >> 7, k = i & 127;
        w3gT[i] = f2bf(W3g[k*256 + ch]);
    }
    for (int i = tid; i < 256*256; i += stride) {        // Wlin [256,256] -> [ch][k]
        const int ch = i >> 8, k = i & 255;
        wlinT[i] = f2bf(Wlin[k*256 + ch]);
    }
}

// ============== fused conv1+conv2+conv3local+mean: one block per glimpse ==============
// LDS (39936 B -> 4 blocks/CU):
//  RegA [0,8704):  sorted pts AoS uint2[512] -> sT[32][136] -> agg2[32][72] -> red[128][9]
//  RegB [8704,19456): aggT[128][16]+sW1g[512] (conv1) -> xs3[32][168]
//  xs16 [19456,37888): [128][72] conv2 A -> HT[64][136]
//  cnt/start/ctr [37888,39424); slc us[128] [39424,39680); cnti [39680,39808); invc [39808,39936)
__global__ __launch_bounds__(256, 4) void k_fused(
    const float* __restrict__ rgb, const float* __restrict__ pos, const float* __restrict__ pos1,
    const float* __restrict__ pos2, const int* __restrict__ idx0, const int* __restrict__ idx1,
    const float* __restrict__ W1l, const float* __restrict__ b1l,
    const float* __restrict__ W1g, const float* __restrict__ b1g,
    const unsigned short* __restrict__ w2lT, const float* __restrict__ b2l,
    const unsigned short* __restrict__ w2gT, const float* __restrict__ b2g,
    const unsigned short* __restrict__ w3lT, const float* __restrict__ b3l,
    unsigned short* __restrict__ aggws)
{
    const int g = blockIdx.x, t = threadIdx.x;
    const int lane = t & 63, wv = t >> 6;
    const int lr = lane & 15, quad = lane >> 4;

    __shared__ __align__(16) unsigned char smem[39936];
    uint2* const spts = (uint2*)smem;                              // [512]
    unsigned short* const sT   = (unsigned short*)smem;            // [32][136]
    unsigned short* const agg2 = (unsigned short*)smem;            // [32][72]
    float* const red  = (float*)smem;                              // [128][9]
    float* const aggT = (float*)(smem + 8704);                     // [128][16]
    float* const sW1g = (float*)(smem + 16896);                    // [512]
    unsigned short* const xs3  = (unsigned short*)(smem + 8704);   // [32][168]
    unsigned short* const xs16 = (unsigned short*)(smem + 19456);  // [128][72]
    unsigned short* const HT   = xs16;                             // [64][136]
    int* const cnt   = (int*)(smem + 37888);
    int* const start = (int*)(smem + 38400);
    int* const ctr   = (int*)(smem + 38912);
    unsigned short* const slc = (unsigned short*)(smem + 39424);
    int* const cnti  = (int*)(smem + 39680);
    float* const invc = (float*)(smem + 39808);

    // ---- pre-B0 setup: sW1g, counters, slc, relpos into xs16, zero xs16 K-pad ----
    for (int i = t; i < 512; i += 256) sW1g[i] = W1g[i];
    if (t < CPG_) cnt[t] = 0;
    if (t < CPG2_) cnti[t] = 0;
    if (t < CPG_) {
        const int c2 = idx1[g*CPG_ + t];
        slc[t] = (unsigned short)(c2 - g*CPG2_);
        #pragma unroll
        for (int d = 0; d < 3; d++)
            xs16[t*72 + 32 + d] = f2bf(pos1[(g*CPG_ + t)*3 + d] - pos2[c2*3 + d]);
    }
    for (int i = t; i < 128*29; i += 256) {     // zero xs16 cols 35..63
        const int r = i / 29, c = 35 + (i - r*29);
        xs16[r*72 + c] = 0;
    }
    __syncthreads();   // B0

    // ---- conv1 A: load 2 points to regs + count ----
    float px0[2], prx[2], pry[2], prz[2];
    int plc[2];
    #pragma unroll
    for (int r = 0; r < 2; r++) {
        const int lp = r*256 + t;
        const int p  = g*NPG_ + lp;
        const int c  = idx0[p];
        plc[r] = c - g*CPG_;
        px0[r] = rgb[p];
        prx[r] = pos[p*3+0] - pos1[c*3+0];
        pry[r] = pos[p*3+1] - pos1[c*3+1];
        prz[r] = pos[p*3+2] - pos1[c*3+2];
        atomicAdd(&cnt[plc[r]], 1);
    }
    if (t < CPG_) atomicAdd(&cnti[slc[t]], 1);
    __syncthreads();   // B1

    // ---- B: wave scan over cnt[128] (scan lives in ctr) ----
    if (t < CPG_) {
        int val = cnt[t];
        const int ln = t & 63;
        #pragma unroll
        for (int d = 1; d < 64; d <<= 1) {
            const int v = __shfl_up(val, d, 64);
            if (ln >= d) val += v;
        }
        ctr[t] = val;
    }
    __syncthreads();   // B2
    if (t >= 64 && t < CPG_) ctr[t] += ctr[63];
    __syncthreads();   // B3
    if (t < CPG_) { const int s = ctr[t] - cnt[t]; start[t] = s; ctr[t] = s; }
    if (t < CPG2_) invc[t] = 1.f / fmaxf((float)cnti[t], 1.f);
    __syncthreads();   // B4

    // ---- C: scatter packed bf16 points into cluster-sorted AoS ----
    #pragma unroll
    for (int r = 0; r < 2; r++) {
        const int slot = atomicAdd(&ctr[plc[r]], 1);
        uint2 pk;
        pk.x = (unsigned)f2bf(px0[r]) | ((unsigned)f2bf(prx[r]) << 16);
        pk.y = (unsigned)f2bf(pry[r]) | ((unsigned)f2bf(prz[r]) << 16);
        spts[slot] = pk;
    }
    __syncthreads();   // B5

    // ---- D: accumulate per cluster (2 threads/cluster), no atomics -> aggT ----
    {
        const int c = t >> 1, ch0 = (t & 1) * 8;
        float wj[8], wx[8], wy[8], wz[8], bb2[8];
        #pragma unroll
        for (int j = 0; j < 8; j++) {
            wj[j] = W1l[ch0+j]; wx[j] = W1l[16+ch0+j];
            wy[j] = W1l[32+ch0+j]; wz[j] = W1l[48+ch0+j];
            bb2[j] = b1l[ch0+j];
        }
        float a[8];
        #pragma unroll
        for (int j = 0; j < 8; j++) a[j] = 0.f;
        const int n = cnt[c], base = start[c];
        for (int i = 0; i < n; i++) {
            const uint2 pk = spts[base + i];
            const float x0 = bflo(pk.x), rx = bfhi(pk.x);
            const float ry = bflo(pk.y), rz = bfhi(pk.y);
            #pragma unroll
            for (int j = 0; j < 8; j++) {
                const float h = bb2[j] + x0*wj[j] + rx*wx[j] + ry*wy[j] + rz*wz[j];
                a[j] += celu_f(h);
            }
        }
        const float inv = 1.f / fmaxf((float)n, 1.f);
        #pragma unroll
        for (int j = 0; j < 8; j++) aggT[c*16 + ch0 + j] = a[j] * inv;
    }
    __syncthreads();   // B6 (spts dead; sT region free)

    // ---- conv1 global conv -> f1 bf16 into xs16 cols 0..31; zero sT ----
    {
        const int oc = t & 31;
        float wreg[16];
        #pragma unroll
        for (int j = 0; j < 16; j++) wreg[j] = sW1g[j*32 + oc];
        const float bg = b1g[oc];
        #pragma unroll
        for (int i = 0; i < 16; i++) {
            const int lc = (t >> 5) + i*8;
            float a = bg;
            #pragma unroll
            for (int j = 0; j < 16; j += 4) {
                const float4 a4 = *(const float4*)&aggT[lc*16 + j];
                a += a4.x*wreg[j] + a4.y*wreg[j+1] + a4.z*wreg[j+2] + a4.w*wreg[j+3];
            }
            xs16[lc*72 + oc] = f2bf(celu_f(a));
        }
    }
    for (int i = t; i < 1088; i += 256) ((uint2*)sT)[i] = make_uint2(0u, 0u);
    __syncthreads();   // B6b
    if (t < CPG_) sT[slc[t]*136 + t] = 0x3F80;   // bf16 1.0
    __syncthreads();   // B7

    // ---- conv2 local MFMA ----
    float hv[8][4];
    {
        const int chn = wv*16 + lr;
        const bf16x8 bw0 = *(const bf16x8*)&w2lT[chn*64 + quad*8];
        const bf16x8 bw1 = *(const bf16x8*)&w2lT[chn*64 + 32 + quad*8];
        const float bias = b2l[chn];
        #pragma unroll
        for (int m = 0; m < 8; m++) {
            f32x4 acc = (f32x4){bias, bias, bias, bias};
            const bf16x8 a0 = *(const bf16x8*)&xs16[(m*16 + lr)*72 + quad*8];
            const bf16x8 a1 = *(const bf16x8*)&xs16[(m*16 + lr)*72 + 32 + quad*8];
            acc = __builtin_amdgcn_mfma_f32_16x16x32_bf16(a0, bw0, acc, 0, 0, 0);
            acc = __builtin_amdgcn_mfma_f32_16x16x32_bf16(a1, bw1, acc, 0, 0, 0);
            #pragma unroll
            for (int r = 0; r < 4; r++) hv[m][r] = celu_f(acc[r]);
        }
    }
    __syncthreads();   // B8 (xs16 dead -> HT; RegB aggT/sW1g dead -> xs3)

    // ---- store H^T; xs3 pads ----
    {
        const int chn = wv*16 + lr;
        #pragma unroll
        for (int m = 0; m < 8; m++) {
            uint2 p;
            p.x = (unsigned)f2bf(hv[m][0]) | ((unsigned)f2bf(hv[m][1]) << 16);
            p.y = (unsigned)f2bf(hv[m][2]) | ((unsigned)f2bf(hv[m][3]) << 16);
            *(uint2*)&HT[chn*136 + m*16 + quad*4] = p;
        }
    }
    if (t < CPG2_) {
        #pragma unroll
        for (int d = 0; d < 3; d++)
            xs3[t*168 + 128 + d] = f2bf(pos2[(g*CPG2_ + t)*3 + d]);
    }
    for (int i = t; i < 32*29; i += 256) {     // zero xs3 cols 131..159
        const int r = i / 29, c = 131 + (i - r*29);
        xs3[r*168 + c] = 0;
    }
    __syncthreads();   // B9

    // ---- segment-sum MFMA agg[32][64] = S^T @ H ----
    float aggv[2][4];
    {
        const int ch = wv*16 + lr;
        f32x4 acc[2];
        acc[0] = (f32x4){0.f, 0.f, 0.f, 0.f};
        acc[1] = (f32x4){0.f, 0.f, 0.f, 0.f};
        #pragma unroll
        for (int ks = 0; ks < 4; ks++) {
            const bf16x8 b = *(const bf16x8*)&HT[ch*136 + ks*32 + quad*8];
            #pragma unroll
            for (int mt = 0; mt < 2; mt++) {
                const bf16x8 a = *(const bf16x8*)&sT[(mt*16 + lr)*136 + ks*32 + quad*8];
                acc[mt] = __builtin_amdgcn_mfma_f32_16x16x32_bf16(a, b, acc[mt], 0, 0, 0);
            }
        }
        #pragma unroll
        for (int mt = 0; mt < 2; mt++)
        #pragma unroll
        for (int r = 0; r < 4; r++)
            aggv[mt][r] = acc[mt][r] * invc[mt*16 + quad*4 + r];
    }
    __syncthreads();   // B10 (sT dead -> agg2)

    {
        const int ch = wv*16 + lr;
        #pragma unroll
        for (int mt = 0; mt < 2; mt++)
        #pragma unroll
        for (int r = 0; r < 4; r++)
            agg2[(mt*16 + quad*4 + r)*72 + ch] = f2bf(aggv[mt][r]);
    }
    __syncthreads();   // B11

    // ---- conv2 global MFMA -> f2 bf16 into xs3 cols 0..127 ----
    {
        f32x4 acc2[2][2];
        int   chn2[2];
        bf16x8 bw[2][2];
        #pragma unroll
        for (int nt = 0; nt < 2; nt++) {
            chn2[nt] = (wv + nt*4)*16 + lr;
            const float bias = b2g[chn2[nt]];
            #pragma unroll
            for (int mt = 0; mt < 2; mt++) acc2[nt][mt] = (f32x4){bias, bias, bias, bias};
            bw[nt][0] = *(const bf16x8*)&w2gT[chn2[nt]*64 + quad*8];
            bw[nt][1] = *(const bf16x8*)&w2gT[chn2[nt]*64 + 32 + quad*8];
        }
        #pragma unroll
        for (int ks = 0; ks < 2; ks++) {
            #pragma unroll
            for (int mt = 0; mt < 2; mt++) {
                const bf16x8 a = *(const bf16x8*)&agg2[(mt*16 + lr)*72 + ks*32 + quad*8];
                acc2[0][mt] = __builtin_amdgcn_mfma_f32_16x16x32_bf16(a, bw[0][ks], acc2[0][mt], 0, 0, 0);
                acc2[1][mt] = __builtin_amdgcn_mfma_f32_16x16x32_bf16(a, bw[1][ks], acc2[1][mt], 0, 0, 0);
            }
        }
        #pragma unroll
        for (int nt = 0; nt < 2; nt++)
        #pragma unroll
        for (int mt = 0; mt < 2; mt++)
        #pragma unroll
        for (int r = 0; r < 4; r++) {
            const int row = mt*16 + quad*4 + r;
            xs3[row*168 + chn2[nt]] = f2bf(celu_f(acc2[nt][mt][r]));
        }
    }
    __syncthreads();   // B12 (agg2 dead -> red)

    // ---- conv3 local MFMA (M=32) -> celu -> partials -> red ----
    {
        f32x4 acc[2][2];
        int chn[2];
        #pragma unroll
        for (int nt = 0; nt < 2; nt++) {
            chn[nt] = (wv + nt*4)*16 + lr;
            const float bias = b3l[chn[nt]];
            #pragma unroll
            for (int mt = 0; mt < 2; mt++) acc[nt][mt] = (f32x4){bias, bias, bias, bias};
        }
        #pragma unroll
        for (int ks = 0; ks < 5; ks++) {
            const bf16x8 b0 = *(const bf16x8*)&w3lT[chn[0]*160 + ks*32 + quad*8];
            const bf16x8 b1 = *(const bf16x8*)&w3lT[chn[1]*160 + ks*32 + quad*8];
            #pragma unroll
            for (int mt = 0; mt < 2; mt++) {
                const bf16x8 a = *(const bf16x8*)&xs3[(mt*16 + lr)*168 + ks*32 + quad*8];
                acc[0][mt] = __builtin_amdgcn_mfma_f32_16x16x32_bf16(a, b0, acc[0][mt], 0, 0, 0);
                acc[1][mt] = __builtin_amdgcn_mfma_f32_16x16x32_bf16(a, b1, acc[1][mt], 0, 0, 0);
            }
        }
        #pragma unroll
        for (int nt = 0; nt < 2; nt++)
        #pragma unroll
        for (int mt = 0; mt < 2; mt++) {
            const float p = celu_f(acc[nt][mt][0]) + celu_f(acc[nt][mt][1])
                          + celu_f(acc[nt][mt][2]) + celu_f(acc[nt][mt][3]);
            red[chn[nt]*9 + mt*4 + quad] = p;
        }
    }
    __syncthreads();   // B13

    // ---- mean -> aggws bf16 ----
    if (t < 128) {
        const float* rp = &red[t*9];
        float a = 0.f;
        #pragma unroll
        for (int p = 0; p < 8; p++) a += rp[p];
        aggws[(size_t)g*128 + t] = f2bf(a * (1.f/32.f));
    }
}

// ============== head: 16 glimpses per block, M=16 fully-valid MFMA ==============
__global__ __launch_bounds__(256) void k_head(
    const unsigned short* __restrict__ aggws,
    const unsigned short* __restrict__ w3gT, const float* __restrict__ b3g,
    const unsigned short* __restrict__ wlinT, const float* __restrict__ blin,
    const float* __restrict__ eps, float* __restrict__ out)
{
    const int g0 = blockIdx.x * 16, t = threadIdx.x;
    const int lane = t & 63, wv = t >> 6;
    const int lr = lane & 15, quad = lane >> 4;
    __shared__ __align__(16) unsigned short aggB[16*136];   // [glimpse row][k=128]
    __shared__ __align__(16) unsigned short f3B[16*264];    // [row][k=256]
    __shared__ float outs[16*260];

    {   // stage agg rows: 256 uint4
        const int row = t >> 4, col8 = (t & 15) * 8;
        const uint4 v = ((const uint4*)aggws)[(size_t)g0*16 + t];
        *(uint4*)&aggB[row*136 + col8] = v;
    }
    __syncthreads();

    // W3g MFMA: C[16 glimpses][256] = aggB @ W3g
    {
        f32x4 c3[4];
        int ch3[4];
        #pragma unroll
        for (int nt = 0; nt < 4; nt++) {
            ch3[nt] = (wv + nt*4)*16 + lr;
            const float bias = b3g[ch3[nt]];
            c3[nt] = (f32x4){bias, bias, bias, bias};
        }
        #pragma unroll
        for (int ks = 0; ks < 4; ks++) {
            const bf16x8 a = *(const bf16x8*)&aggB[lr*136 + ks*32 + quad*8];
            #pragma unroll
            for (int nt = 0; nt < 4; nt++) {
                const bf16x8 b = *(const bf16x8*)&w3gT[ch3[nt]*128 + ks*32 + quad*8];
                c3[nt] = __builtin_amdgcn_mfma_f32_16x16x32_bf16(a, b, c3[nt], 0, 0, 0);
            }
        }
        #pragma unroll
        for (int nt = 0; nt < 4; nt++)
        #pragma unroll
        for (int r = 0; r < 4; r++) {
            const int row = quad*4 + r;                     // glimpse g0+row
            const float v = celu_f(c3[nt][r]);
            out[OFF_F + (size_t)(g0 + row)*256 + ch3[nt]] = v;
            f3B[row*264 + ch3[nt]] = f2bf(v);
        }
    }
    __syncthreads();

    // Wlin MFMA: C[16][256] = f3B @ Wlin
    {
        f32x4 cl[4];
        int ch4[4];
        #pragma unroll
        for (int nt = 0; nt < 4; nt++) {
            ch4[nt] = (wv + nt*4)*16 + lr;
            const float bias = blin[ch4[nt]];
            cl[nt] = (f32x4){bias, bias, bias, bias};
        }
        #pragma unroll
        for (int ks = 0; ks < 8; ks++) {
            const bf16x8 a = *(const bf16x8*)&f3B[lr*264 + ks*32 + quad*8];
            #pragma unroll
            for (int nt = 0; nt < 4; nt++) {
                const bf16x8 b = *(const bf16x8*)&wlinT[ch4[nt]*256 + ks*32 + quad*8];
                cl[nt] = __builtin_amdgcn_mfma_f32_16x16x32_bf16(a, b, cl[nt], 0, 0, 0);
            }
        }
        #pragma unroll
        for (int nt = 0; nt < 4; nt++)
        #pragma unroll
        for (int r = 0; r < 4; r++)
            outs[(quad*4 + r)*260 + ch4[nt]] = cl[nt][r];
    }
    __syncthreads();

    // sample: 16 glimpses x 128 ch
    for (int i = t; i < 2048; i += 256) {
        const int gl = i >> 7, ch = i & 127;
        const int g = g0 + gl;
        const float mu    = outs[gl*260 + ch];
        const float sigma = softplus_f(outs[gl*260 + 128 + ch]);
        const float z     = mu + sigma * eps[g*128 + ch];
        out[OFF_MU + (size_t)g*128 + ch] = mu;
        out[OFF_SG + (size_t)g*128 + ch] = sigma;
        if (ch < 64) out[OFF_ZW + (size_t)g*64 + ch] = z;
        else         out[OFF_ZM + (size_t)g*64 + (ch - 64)] = z;
    }
}

extern "C" void kernel_launch(void* const* d_in, const int* in_sizes, int n_in,
                              void* d_out, int out_size, void* d_ws, size_t ws_size,
                              hipStream_t stream)
{
    const float* rgb  = (const float*)d_in[0];
    const float* pos  = (const float*)d_in[1];
    const float* pos1 = (const float*)d_in[2];
    const float* pos2 = (const float*)d_in[3];
    const int*   idx0 = (const int*)d_in[4];
    const int*   idx1 = (const int*)d_in[5];
    const float* eps  = (const float*)d_in[7];
    const float* W1l = (const float*)d_in[8],  *b1l = (const float*)d_in[9];
    const float* W1g = (const float*)d_in[10], *b1g = (const float*)d_in[11];
    const float* W2l = (const float*)d_in[12], *b2l = (const float*)d_in[13];
    const float* W2g = (const float*)d_in[14], *b2g = (const float*)d_in[15];
    const float* W3l = (const float*)d_in[16], *b3l = (const float*)d_in[17];
    const float* W3g = (const float*)d_in[18], *b3g = (const float*)d_in[19];
    const float* Wlin = (const float*)d_in[20], *blin = (const float*)d_in[21];

    unsigned short* w2lT  = (unsigned short*)d_ws;       // 64*64
    unsigned short* w2gT  = w2lT + 64*64;                // 128*64
    unsigned short* w3lT  = w2gT + 128*64;               // 128*160
    unsigned short* w3gT  = w3lT + 128*160;              // 256*128
    unsigned short* wlinT = w3gT + 256*128;              // 256*256
    unsigned short* aggws = wlinT + 256*256;             // G*128 bf16
    float* outp = (float*)d_out;

    k_prep <<<64,    256, 0, stream>>>(W2l, W2g, W3l, W3g, Wlin, w2lT, w2gT, w3lT, w3gT, wlinT);
    k_fused<<<G_,    256, 0, stream>>>(rgb, pos, pos1, pos2, idx0, idx1,
                                       W1l, b1l, W1g, b1g,
                                       w2lT, b2l, w2gT, b2g, w3lT, b3l, aggws);
    k_head <<<G_/16, 256, 0, stream>>>(aggws, w3gT, b3g, wlinT, blin, eps, outp);
}

// Round 13
// 158.359 us; speedup vs baseline: 1.2467x; 1.0187x over previous
//
#include <hip/hip_runtime.h>
#include <hip/hip_bf16.h>
#include <cstddef>

#define G_   2048
#define NPG_ 512
#define CPG_ 128
#define CPG2_ 32

// output layout (floats): z_what[G,64] | z_mask[G,64] | mu[G,128] | sigma[G,128] | f[G,256]
#define OFF_ZW 0
#define OFF_ZM (G_*64)
#define OFF_MU (2*G_*64)
#define OFF_SG (2*G_*64 + G_*128)
#define OFF_F  (2*G_*64 + 2*G_*128)

typedef __attribute__((ext_vector_type(8))) short bf16x8;
typedef __attribute__((ext_vector_type(4))) float f32x4;

__device__ __forceinline__ float celu_f(float x)     { return x > 0.f ? x : __expf(x) - 1.f; }
__device__ __forceinline__ float softplus_f(float x) { return fmaxf(x, 0.f) + __logf(1.f + __expf(-fabsf(x))); }
__device__ __forceinline__ unsigned short f2bf(float x) {
    __hip_bfloat16 h = __float2bfloat16(x);
    return *reinterpret_cast<unsigned short*>(&h);
}
__device__ __forceinline__ float bflo(unsigned w) { return __uint_as_float(w << 16); }
__device__ __forceinline__ float bfhi(unsigned w) { return __uint_as_float(w & 0xffff0000u); }

// ---------------- prep: transposed, zero-K-padded bf16 weight copies in ws ----------------
__global__ void k_prep(const float* __restrict__ W2l, const float* __restrict__ W2g,
                       const float* __restrict__ W3l, const float* __restrict__ W3g,
                       const float* __restrict__ Wlin, const float* __restrict__ W1g,
                       unsigned short* __restrict__ w2lT, unsigned short* __restrict__ w2gT,
                       unsigned short* __restrict__ w3lT, unsigned short* __restrict__ w3gT,
                       unsigned short* __restrict__ wlinT, unsigned short* __restrict__ w1gT)
{
    const int tid = blockIdx.x*256 + threadIdx.x, stride = gridDim.x*256;
    for (int i = tid; i < 64*64; i += stride) {          // W2l [35,64] -> [ch][k=64pad]
        const int ch = i >> 6, k = i & 63;
        w2lT[i] = f2bf(k < 35 ? W2l[k*64 + ch] : 0.f);
    }
    for (int i = tid; i < 128*64; i += stride) {         // W2g [64,128] -> [ch][k]
        const int ch = i >> 6, k = i & 63;
        w2gT[i] = f2bf(W2g[k*128 + ch]);
    }
    for (int i = tid; i < 128*160; i += stride) {        // W3l [131,128] -> [ch][k=160pad]
        const int ch = i / 160, k = i % 160;
        w3lT[i] = f2bf(k < 131 ? W3l[k*128 + ch] : 0.f);
    }
    for (int i = tid; i < 256*128; i += stride) {        // W3g [128,256] -> [ch][k]
        const int ch = i >> 7, k = i & 127;
        w3gT[i] = f2bf(W3g[k*256 + ch]);
    }
    for (int i = tid; i < 256*256; i += stride) {        // Wlin [256,256] -> [ch][k]
        const int ch = i >> 8, k = i & 255;
        wlinT[i] = f2bf(Wlin[k*256 + ch]);
    }
    for (int i = tid; i < 32*40; i += stride) {          // W1g [16,32] -> [ch][k=40pad]
        const int ch = i / 40, k = i % 40;
        w1gT[i] = f2bf(k < 16 ? W1g[k*32 + ch] : 0.f);
    }
}

// ============== fused conv1+conv2+conv3local+mean: one block per glimpse ==============
// LDS (29184 B -> 5 blocks/CU), phase overlays:
//  Region1 @0 (18432): spts[512]u2 @0 + aggT us[128][40] @4096 (conv1)
//                      -> xs16 us[128][72] -> HT us[64][136] -> xs3 us[32][168]
//  Region2 @18432 (8704): sT us[32][136] -> agg2 us[32][72] -> red f32[128][9]
//  Region3 @27136: cnt/start/ctr int[128]x3, slc us[128], cnti int[32], invc f32[32]
__global__ __launch_bounds__(256, 5) void k_fused(
    const float* __restrict__ rgb, const float* __restrict__ pos, const float* __restrict__ pos1,
    const float* __restrict__ pos2, const int* __restrict__ idx0, const int* __restrict__ idx1,
    const float* __restrict__ W1l, const float* __restrict__ b1l,
    const unsigned short* __restrict__ w1gT, const float* __restrict__ b1g,
    const unsigned short* __restrict__ w2lT, const float* __restrict__ b2l,
    const unsigned short* __restrict__ w2gT, const float* __restrict__ b2g,
    const unsigned short* __restrict__ w3lT, const float* __restrict__ b3l,
    unsigned short* __restrict__ aggws)
{
    const int g = blockIdx.x, t = threadIdx.x;
    const int lane = t & 63, wv = t >> 6;
    const int lr = lane & 15, quad = lane >> 4;

    __shared__ __align__(16) unsigned char smem[29184];
    uint2* const spts = (uint2*)smem;                              // [512]
    unsigned short* const aggT = (unsigned short*)(smem + 4096);   // [128][40]
    unsigned short* const xs16 = (unsigned short*)smem;            // [128][72]
    unsigned short* const HT   = (unsigned short*)smem;            // [64][136]
    unsigned short* const xs3  = (unsigned short*)smem;            // [32][168]
    unsigned short* const sT   = (unsigned short*)(smem + 18432);  // [32][136]
    unsigned short* const agg2 = (unsigned short*)(smem + 18432);  // [32][72]
    float* const red  = (float*)(smem + 18432);                    // [128][9]
    int* const cnt   = (int*)(smem + 27136);
    int* const start = (int*)(smem + 27648);
    int* const ctr   = (int*)(smem + 28160);
    unsigned short* const slc = (unsigned short*)(smem + 28672);
    int* const cnti  = (int*)(smem + 28928);
    float* const invc = (float*)(smem + 29056);

    // ---- pre-B0: counters, slc + rel regs, zero sT, zero aggT K-pad cols 16..31 ----
    if (t < CPG_) cnt[t] = 0;
    if (t < CPG2_) cnti[t] = 0;
    float relx = 0.f, rely = 0.f, relz = 0.f;
    if (t < CPG_) {
        const int c2 = idx1[g*CPG_ + t];
        slc[t] = (unsigned short)(c2 - g*CPG2_);
        relx = pos1[(g*CPG_ + t)*3 + 0] - pos2[c2*3 + 0];
        rely = pos1[(g*CPG_ + t)*3 + 1] - pos2[c2*3 + 1];
        relz = pos1[(g*CPG_ + t)*3 + 2] - pos2[c2*3 + 2];
    }
    for (int i = t; i < 2176; i += 256) ((unsigned*)sT)[i] = 0u;
    for (int i = t; i < 128*8; i += 256) {
        const int r = i >> 3, j = i & 7;
        ((unsigned*)aggT)[r*20 + 8 + j] = 0u;
    }
    __syncthreads();   // B0

    // ---- conv1 A: load 2 points to regs + count; one-hot scatter into sT ----
    if (t < CPG_) sT[slc[t]*136 + t] = 0x3F80;   // bf16 1.0
    float px0[2], prx[2], pry[2], prz[2];
    int plc[2];
    #pragma unroll
    for (int r = 0; r < 2; r++) {
        const int lp = r*256 + t;
        const int p  = g*NPG_ + lp;
        const int c  = idx0[p];
        plc[r] = c - g*CPG_;
        px0[r] = rgb[p];
        prx[r] = pos[p*3+0] - pos1[c*3+0];
        pry[r] = pos[p*3+1] - pos1[c*3+1];
        prz[r] = pos[p*3+2] - pos1[c*3+2];
        atomicAdd(&cnt[plc[r]], 1);
    }
    if (t < CPG_) atomicAdd(&cnti[slc[t]], 1);
    __syncthreads();   // B1

    // ---- scan (into ctr) ----
    if (t < CPG_) {
        int val = cnt[t];
        const int ln = t & 63;
        #pragma unroll
        for (int d = 1; d < 64; d <<= 1) {
            const int v = __shfl_up(val, d, 64);
            if (ln >= d) val += v;
        }
        ctr[t] = val;
    }
    __syncthreads();   // B2
    // ---- fixup + start + invc ----
    if (t < CPG_) {
        int v = ctr[t];
        if (t >= 64) v += ctr[63];
        const int s = v - cnt[t];
        start[t] = s; ctr[t] = s;
    }
    if (t < CPG2_) invc[t] = 1.f / fmaxf((float)cnti[t], 1.f);
    __syncthreads();   // B3

    // ---- C: scatter packed bf16 points into cluster-sorted AoS ----
    #pragma unroll
    for (int r = 0; r < 2; r++) {
        const int slot = atomicAdd(&ctr[plc[r]], 1);
        uint2 pk;
        pk.x = (unsigned)f2bf(px0[r]) | ((unsigned)f2bf(prx[r]) << 16);
        pk.y = (unsigned)f2bf(pry[r]) | ((unsigned)f2bf(prz[r]) << 16);
        spts[slot] = pk;
    }
    __syncthreads();   // B4

    // ---- D: accumulate per cluster (2 threads/cluster) -> aggT bf16 cols 0..15 ----
    {
        const int c = t >> 1, ch0 = (t & 1) * 8;
        float wj[8], wx[8], wy[8], wz[8], bb2[8];
        #pragma unroll
        for (int j = 0; j < 8; j++) {
            wj[j] = W1l[ch0+j]; wx[j] = W1l[16+ch0+j];
            wy[j] = W1l[32+ch0+j]; wz[j] = W1l[48+ch0+j];
            bb2[j] = b1l[ch0+j];
        }
        float a[8];
        #pragma unroll
        for (int j = 0; j < 8; j++) a[j] = 0.f;
        const int n = cnt[c], base = start[c];
        for (int i = 0; i < n; i++) {
            const uint2 pk = spts[base + i];
            const float x0 = bflo(pk.x), rx = bfhi(pk.x);
            const float ry = bflo(pk.y), rz = bfhi(pk.y);
            #pragma unroll
            for (int j = 0; j < 8; j++) {
                const float h = bb2[j] + x0*wj[j] + rx*wx[j] + ry*wy[j] + rz*wz[j];
                a[j] += celu_f(h);
            }
        }
        const float inv = 1.f / fmaxf((float)n, 1.f);
        uint2 q0, q1;
        q0.x = (unsigned)f2bf(a[0]*inv) | ((unsigned)f2bf(a[1]*inv) << 16);
        q0.y = (unsigned)f2bf(a[2]*inv) | ((unsigned)f2bf(a[3]*inv) << 16);
        q1.x = (unsigned)f2bf(a[4]*inv) | ((unsigned)f2bf(a[5]*inv) << 16);
        q1.y = (unsigned)f2bf(a[6]*inv) | ((unsigned)f2bf(a[7]*inv) << 16);
        *(uint2*)&aggT[c*40 + ch0]     = q0;
        *(uint2*)&aggT[c*40 + ch0 + 4] = q1;
    }
    __syncthreads();   // B5

    // ---- conv1 global conv MFMA: [128,32(K pad)] @ w1gT -> C regs ----
    f32x4 c1[2][2];    // [nt][mt]
    {
        #pragma unroll
        for (int nt = 0; nt < 2; nt++) {
            const float bias = b1g[nt*16 + lr];
            c1[nt][0] = (f32x4){bias, bias, bias, bias};
            c1[nt][1] = (f32x4){bias, bias, bias, bias};
        }
        const bf16x8 b0 = *(const bf16x8*)&w1gT[(0*16 + lr)*40 + quad*8];
        const bf16x8 b1 = *(const bf16x8*)&w1gT[(1*16 + lr)*40 + quad*8];
        #pragma unroll
        for (int mt = 0; mt < 2; mt++) {
            const bf16x8 a = *(const bf16x8*)&aggT[((2*wv + mt)*16 + lr)*40 + quad*8];
            c1[0][mt] = __builtin_amdgcn_mfma_f32_16x16x32_bf16(a, b0, c1[0][mt], 0, 0, 0);
            c1[1][mt] = __builtin_amdgcn_mfma_f32_16x16x32_bf16(a, b1, c1[1][mt], 0, 0, 0);
        }
    }
    __syncthreads();   // B6 (spts/aggT dead; Region1 -> xs16)

    // ---- write f1 into xs16 cols 0..31, relpos cols 32..34, zero 35..63 ----
    #pragma unroll
    for (int nt = 0; nt < 2; nt++)
    #pragma unroll
    for (int mt = 0; mt < 2; mt++)
    #pragma unroll
    for (int r = 0; r < 4; r++) {
        const int cl = (2*wv + mt)*16 + quad*4 + r;
        xs16[cl*72 + nt*16 + lr] = f2bf(celu_f(c1[nt][mt][r]));
    }
    if (t < CPG_) {
        xs16[t*72 + 32] = f2bf(relx);
        xs16[t*72 + 33] = f2bf(rely);
        xs16[t*72 + 34] = f2bf(relz);
    }
    for (int i = t; i < 128*29; i += 256) {
        const int r = i / 29, c = 35 + (i - r*29);
        xs16[r*72 + c] = 0;
    }
    __syncthreads();   // B7

    // ---- conv2 local MFMA ----
    float hv[8][4];
    {
        const int chn = wv*16 + lr;
        const bf16x8 bw0 = *(const bf16x8*)&w2lT[chn*64 + quad*8];
        const bf16x8 bw1 = *(const bf16x8*)&w2lT[chn*64 + 32 + quad*8];
        const float bias = b2l[chn];
        #pragma unroll
        for (int m = 0; m < 8; m++) {
            f32x4 acc = (f32x4){bias, bias, bias, bias};
            const bf16x8 a0 = *(const bf16x8*)&xs16[(m*16 + lr)*72 + quad*8];
            const bf16x8 a1 = *(const bf16x8*)&xs16[(m*16 + lr)*72 + 32 + quad*8];
            acc = __builtin_amdgcn_mfma_f32_16x16x32_bf16(a0, bw0, acc, 0, 0, 0);
            acc = __builtin_amdgcn_mfma_f32_16x16x32_bf16(a1, bw1, acc, 0, 0, 0);
            #pragma unroll
            for (int r = 0; r < 4; r++) hv[m][r] = celu_f(acc[r]);
        }
    }
    __syncthreads();   // B8 (xs16 dead -> HT)

    // ---- store H^T ----
    {
        const int chn = wv*16 + lr;
        #pragma unroll
        for (int m = 0; m < 8; m++) {
            uint2 p;
            p.x = (unsigned)f2bf(hv[m][0]) | ((unsigned)f2bf(hv[m][1]) << 16);
            p.y = (unsigned)f2bf(hv[m][2]) | ((unsigned)f2bf(hv[m][3]) << 16);
            *(uint2*)&HT[chn*136 + m*16 + quad*4] = p;
        }
    }
    __syncthreads();   // B9

    // ---- segment-sum MFMA agg[32][64] = S^T @ H ----
    float aggv[2][4];
    {
        const int ch = wv*16 + lr;
        f32x4 acc[2];
        acc[0] = (f32x4){0.f, 0.f, 0.f, 0.f};
        acc[1] = (f32x4){0.f, 0.f, 0.f, 0.f};
        #pragma unroll
        for (int ks = 0; ks < 4; ks++) {
            const bf16x8 b = *(const bf16x8*)&HT[ch*136 + ks*32 + quad*8];
            #pragma unroll
            for (int mt = 0; mt < 2; mt++) {
                const bf16x8 a = *(const bf16x8*)&sT[(mt*16 + lr)*136 + ks*32 + quad*8];
                acc[mt] = __builtin_amdgcn_mfma_f32_16x16x32_bf16(a, b, acc[mt], 0, 0, 0);
            }
        }
        #pragma unroll
        for (int mt = 0; mt < 2; mt++)
        #pragma unroll
        for (int r = 0; r < 4; r++)
            aggv[mt][r] = acc[mt][r] * invc[mt*16 + quad*4 + r];
    }
    __syncthreads();   // B10 (sT dead -> agg2; HT dead -> xs3)

    // ---- agg2 stores (Region2) + xs3 pads/zeros (Region1) ----
    {
        const int ch = wv*16 + lr;
        #pragma unroll
        for (int mt = 0; mt < 2; mt++)
        #pragma unroll
        for (int r = 0; r < 4; r++)
            agg2[(mt*16 + quad*4 + r)*72 + ch] = f2bf(aggv[mt][r]);
    }
    if (t < CPG2_) {
        #pragma unroll
        for (int d = 0; d < 3; d++)
            xs3[t*168 + 128 + d] = f2bf(pos2[(g*CPG2_ + t)*3 + d]);
    }
    for (int i = t; i < 32*29; i += 256) {
        const int r = i / 29, c = 131 + (i - r*29);
        xs3[r*168 + c] = 0;
    }
    __syncthreads();   // B11

    // ---- conv2 global MFMA -> f2 bf16 into xs3 cols 0..127 ----
    {
        f32x4 acc2[2][2];
        int   chn2[2];
        bf16x8 bw[2][2];
        #pragma unroll
        for (int nt = 0; nt < 2; nt++) {
            chn2[nt] = (wv + nt*4)*16 + lr;
            const float bias = b2g[chn2[nt]];
            #pragma unroll
            for (int mt = 0; mt < 2; mt++) acc2[nt][mt] = (f32x4){bias, bias, bias, bias};
            bw[nt][0] = *(const bf16x8*)&w2gT[chn2[nt]*64 + quad*8];
            bw[nt][1] = *(const bf16x8*)&w2gT[chn2[nt]*64 + 32 + quad*8];
        }
        #pragma unroll
        for (int ks = 0; ks < 2; ks++) {
            #pragma unroll
            for (int mt = 0; mt < 2; mt++) {
                const bf16x8 a = *(const bf16x8*)&agg2[(mt*16 + lr)*72 + ks*32 + quad*8];
                acc2[0][mt] = __builtin_amdgcn_mfma_f32_16x16x32_bf16(a, bw[0][ks], acc2[0][mt], 0, 0, 0);
                acc2[1][mt] = __builtin_amdgcn_mfma_f32_16x16x32_bf16(a, bw[1][ks], acc2[1][mt], 0, 0, 0);
            }
        }
        #pragma unroll
        for (int nt = 0; nt < 2; nt++)
        #pragma unroll
        for (int mt = 0; mt < 2; mt++)
        #pragma unroll
        for (int r = 0; r < 4; r++) {
            const int row = mt*16 + quad*4 + r;
            xs3[row*168 + chn2[nt]] = f2bf(celu_f(acc2[nt][mt][r]));
        }
    }
    __syncthreads();   // B12 (agg2 dead -> red)

    // ---- conv3 local MFMA (M=32) -> celu -> partials -> red ----
    {
        f32x4 acc[2][2];
        int chn[2];
        #pragma unroll
        for (int nt = 0; nt < 2; nt++) {
            chn[nt] = (wv + nt*4)*16 + lr;
            const float bias = b3l[chn[nt]];
            #pragma unroll
            for (int mt = 0; mt < 2; mt++) acc[nt][mt] = (f32x4){bias, bias, bias, bias};
        }
        #pragma unroll
        for (int ks = 0; ks < 5; ks++) {
            const bf16x8 b0 = *(const bf16x8*)&w3lT[chn[0]*160 + ks*32 + quad*8];
            const bf16x8 b1 = *(const bf16x8*)&w3lT[chn[1]*160 + ks*32 + quad*8];
            #pragma unroll
            for (int mt = 0; mt < 2; mt++) {
                const bf16x8 a = *(const bf16x8*)&xs3[(mt*16 + lr)*168 + ks*32 + quad*8];
                acc[0][mt] = __builtin_amdgcn_mfma_f32_16x16x32_bf16(a, b0, acc[0][mt], 0, 0, 0);
                acc[1][mt] = __builtin_amdgcn_mfma_f32_16x16x32_bf16(a, b1, acc[1][mt], 0, 0, 0);
            }
        }
        #pragma unroll
        for (int nt = 0; nt < 2; nt++)
        #pragma unroll
        for (int mt = 0; mt < 2; mt++) {
            const float p = celu_f(acc[nt][mt][0]) + celu_f(acc[nt][mt][1])
                          + celu_f(acc[nt][mt][2]) + celu_f(acc[nt][mt][3]);
            red[chn[nt]*9 + mt*4 + quad] = p;
        }
    }
    __syncthreads();   // B13

    // ---- mean -> aggws bf16 ----
    if (t < 128) {
        const float* rp = &red[t*9];
        float a = 0.f;
        #pragma unroll
        for (int p = 0; p < 8; p++) a += rp[p];
        aggws[(size_t)g*128 + t] = f2bf(a * (1.f/32.f));
    }
}

// ============== head: 16 glimpses per block, M=16 fully-valid MFMA ==============
__global__ __launch_bounds__(256) void k_head(
    const unsigned short* __restrict__ aggws,
    const unsigned short* __restrict__ w3gT, const float* __restrict__ b3g,
    const unsigned short* __restrict__ wlinT, const float* __restrict__ blin,
    const float* __restrict__ eps, float* __restrict__ out)
{
    const int g0 = blockIdx.x * 16, t = threadIdx.x;
    const int lane = t & 63, wv = t >> 6;
    const int lr = lane & 15, quad = lane >> 4;
    __shared__ __align__(16) unsigned short aggB[16*136];
    __shared__ __align__(16) unsigned short f3B[16*264];
    __shared__ float outs[16*260];

    {   // stage agg rows: 256 uint4
        const int row = t >> 4, col8 = (t & 15) * 8;
        const uint4 v = ((const uint4*)aggws)[(size_t)g0*16 + t];
        *(uint4*)&aggB[row*136 + col8] = v;
    }
    __syncthreads();

    // W3g MFMA: C[16 glimpses][256] = aggB @ W3g
    {
        f32x4 c3[4];
        int ch3[4];
        #pragma unroll
        for (int nt = 0; nt < 4; nt++) {
            ch3[nt] = (wv + nt*4)*16 + lr;
            const float bias = b3g[ch3[nt]];
            c3[nt] = (f32x4){bias, bias, bias, bias};
        }
        #pragma unroll
        for (int ks = 0; ks < 4; ks++) {
            const bf16x8 a = *(const bf16x8*)&aggB[lr*136 + ks*32 + quad*8];
            #pragma unroll
            for (int nt = 0; nt < 4; nt++) {
                const bf16x8 b = *(const bf16x8*)&w3gT[ch3[nt]*128 + ks*32 + quad*8];
                c3[nt] = __builtin_amdgcn_mfma_f32_16x16x32_bf16(a, b, c3[nt], 0, 0, 0);
            }
        }
        #pragma unroll
        for (int nt = 0; nt < 4; nt++)
        #pragma unroll
        for (int r = 0; r < 4; r++) {
            const int row = quad*4 + r;
            const float v = celu_f(c3[nt][r]);
            out[OFF_F + (size_t)(g0 + row)*256 + ch3[nt]] = v;
            f3B[row*264 + ch3[nt]] = f2bf(v);
        }
    }
    __syncthreads();

    // Wlin MFMA: C[16][256] = f3B @ Wlin
    {
        f32x4 cl[4];
        int ch4[4];
        #pragma unroll
        for (int nt = 0; nt < 4; nt++) {
            ch4[nt] = (wv + nt*4)*16 + lr;
            const float bias = blin[ch4[nt]];
            cl[nt] = (f32x4){bias, bias, bias, bias};
        }
        #pragma unroll
        for (int ks = 0; ks < 8; ks++) {
            const bf16x8 a = *(const bf16x8*)&f3B[lr*264 + ks*32 + quad*8];
            #pragma unroll
            for (int nt = 0; nt < 4; nt++) {
                const bf16x8 b = *(const bf16x8*)&wlinT[ch4[nt]*256 + ks*32 + quad*8];
                cl[nt] = __builtin_amdgcn_mfma_f32_16x16x32_bf16(a, b, cl[nt], 0, 0, 0);
            }
        }
        #pragma unroll
        for (int nt = 0; nt < 4; nt++)
        #pragma unroll
        for (int r = 0; r < 4; r++)
            outs[(quad*4 + r)*260 + ch4[nt]] = cl[nt][r];
    }
    __syncthreads();

    // sample: 16 glimpses x 128 ch
    for (int i = t; i < 2048; i += 256) {
        const int gl = i >> 7, ch = i & 127;
        const int g = g0 + gl;
        const float mu    = outs[gl*260 + ch];
        const float sigma = softplus_f(outs[gl*260 + 128 + ch]);
        const float z     = mu + sigma * eps[g*128 + ch];
        out[OFF_MU + (size_t)g*128 + ch] = mu;
        out[OFF_SG + (size_t)g*128 + ch] = sigma;
        if (ch < 64) out[OFF_ZW + (size_t)g*64 + ch] = z;
        else         out[OFF_ZM + (size_t)g*64 + (ch - 64)] = z;
    }
}

extern "C" void kernel_launch(void* const* d_in, const int* in_sizes, int n_in,
                              void* d_out, int out_size, void* d_ws, size_t ws_size,
                              hipStream_t stream)
{
    const float* rgb  = (const float*)d_in[0];
    const float* pos  = (const float*)d_in[1];
    const float* pos1 = (const float*)d_in[2];
    const float* pos2 = (const float*)d_in[3];
    const int*   idx0 = (const int*)d_in[4];
    const int*   idx1 = (const int*)d_in[5];
    const float* eps  = (const float*)d_in[7];
    const float* W1l = (const float*)d_in[8],  *b1l = (const float*)d_in[9];
    const float* W1g = (const float*)d_in[10], *b1g = (const float*)d_in[11];
    const float* W2l = (const float*)d_in[12], *b2l = (const float*)d_in[13];
    const float* W2g = (const float*)d_in[14], *b2g = (const float*)d_in[15];
    const float* W3l = (const float*)d_in[16], *b3l = (const float*)d_in[17];
    const float* W3g = (const float*)d_in[18], *b3g = (const float*)d_in[19];
    const float* Wlin = (const float*)d_in[20], *blin = (const float*)d_in[21];

    unsigned short* w2lT  = (unsigned short*)d_ws;       // 64*64
    unsigned short* w2gT  = w2lT + 64*64;                // 128*64
    unsigned short* w3lT  = w2gT + 128*64;               // 128*160
    unsigned short* w3gT  = w3lT + 128*160;              // 256*128
    unsigned short* wlinT = w3gT + 256*128;              // 256*256
    unsigned short* w1gT  = wlinT + 256*256;             // 32*40
    unsigned short* aggws = w1gT + 32*40;                // G*128 bf16
    float* outp = (float*)d_out;

    k_prep <<<64,    256, 0, stream>>>(W2l, W2g, W3l, W3g, Wlin, W1g,
                                       w2lT, w2gT, w3lT, w3gT, wlinT, w1gT);
    k_fused<<<G_,    256, 0, stream>>>(rgb, pos, pos1, pos2, idx0, idx1,
                                       W1l, b1l, w1gT, b1g,
                                       w2lT, b2l, w2gT, b2g, w3lT, b3l, aggws);
    k_head <<<G_/16, 256, 0, stream>>>(aggws, w3gT, b3g, wlinT, blin, eps, outp);
}

// Round 14
// 157.592 us; speedup vs baseline: 1.2528x; 1.0049x over previous
//
#include <hip/hip_runtime.h>
#include <hip/hip_bf16.h>
#include <cstddef>

#define G_   2048
#define NPG_ 512
#define CPG_ 128
#define CPG2_ 32

// output layout (floats): z_what[G,64] | z_mask[G,64] | mu[G,128] | sigma[G,128] | f[G,256]
#define OFF_ZW 0
#define OFF_ZM (G_*64)
#define OFF_MU (2*G_*64)
#define OFF_SG (2*G_*64 + G_*128)
#define OFF_F  (2*G_*64 + 2*G_*128)

typedef __attribute__((ext_vector_type(8))) short bf16x8;
typedef __attribute__((ext_vector_type(4))) float f32x4;

__device__ __forceinline__ float celu_f(float x)     { return x > 0.f ? x : __expf(x) - 1.f; }
__device__ __forceinline__ float softplus_f(float x) { return fmaxf(x, 0.f) + __logf(1.f + __expf(-fabsf(x))); }
// fast RNE fp32->bf16 (finite inputs): identical result to __float2bfloat16
__device__ __forceinline__ unsigned short f2bf(float x) {
    unsigned u = __float_as_uint(x);
    u += 0x7FFFu + ((u >> 16) & 1u);
    return (unsigned short)(u >> 16);
}
__device__ __forceinline__ unsigned pack2(float a, float b) {   // bf16(a) | bf16(b)<<16
    unsigned ua = __float_as_uint(a); ua += 0x7FFFu + ((ua >> 16) & 1u);
    unsigned ub = __float_as_uint(b); ub += 0x7FFFu + ((ub >> 16) & 1u);
    return (ua >> 16) | (ub & 0xFFFF0000u);
}
__device__ __forceinline__ float bflo(unsigned w) { return __uint_as_float(w << 16); }
__device__ __forceinline__ float bfhi(unsigned w) { return __uint_as_float(w & 0xffff0000u); }

// ---------------- prep: transposed, zero-K-padded bf16 weight copies in ws ----------------
__global__ void k_prep(const float* __restrict__ W2l, const float* __restrict__ W2g,
                       const float* __restrict__ W3l, const float* __restrict__ W3g,
                       const float* __restrict__ Wlin, const float* __restrict__ W1g,
                       unsigned short* __restrict__ w2lT, unsigned short* __restrict__ w2gT,
                       unsigned short* __restrict__ w3lT, unsigned short* __restrict__ w3gT,
                       unsigned short* __restrict__ wlinT, unsigned short* __restrict__ w1gT)
{
    const int tid = blockIdx.x*256 + threadIdx.x, stride = gridDim.x*256;
    for (int i = tid; i < 64*64; i += stride) {          // W2l [35,64] -> [ch][k=64pad]
        const int ch = i >> 6, k = i & 63;
        w2lT[i] = f2bf(k < 35 ? W2l[k*64 + ch] : 0.f);
    }
    for (int i = tid; i < 128*64; i += stride) {         // W2g [64,128] -> [ch][k]
        const int ch = i >> 6, k = i & 63;
        w2gT[i] = f2bf(W2g[k*128 + ch]);
    }
    for (int i = tid; i < 128*160; i += stride) {        // W3l [131,128] -> [ch][k=160pad]
        const int ch = i / 160, k = i % 160;
        w3lT[i] = f2bf(k < 131 ? W3l[k*128 + ch] : 0.f);
    }
    for (int i = tid; i < 256*128; i += stride) {        // W3g [128,256] -> [ch][k]
        const int ch = i >> 7, k = i & 127;
        w3gT[i] = f2bf(W3g[k*256 + ch]);
    }
    for (int i = tid; i < 256*256; i += stride) {        // Wlin [256,256] -> [ch][k]
        const int ch = i >> 8, k = i & 255;
        wlinT[i] = f2bf(Wlin[k*256 + ch]);
    }
    for (int i = tid; i < 32*40; i += stride) {          // W1g [16,32] -> [ch][k=40pad]
        const int ch = i / 40, k = i % 40;
        w1gT[i] = f2bf(k < 16 ? W1g[k*32 + ch] : 0.f);
    }
}

// ============== fused conv1+conv2+conv3local+mean: one block per glimpse ==============
// LDS (29184 B -> 5 blocks/CU), phase overlays:
//  Region1 @0 (18432): spts[512]u2 @0 + aggT us[128][40] @4096 (conv1)
//                      -> xs16 us[128][72] -> HT us[64][136] -> xs3 us[32][168]
//  Region2 @18432 (8704): sT us[32][136] -> agg2 us[32][72] -> red f32[128][9]
//  Region3 @27136: cnt/start/ctr int[128]x3, slc us[128], cnti int[32], invc f32[32]
__global__ __launch_bounds__(256, 5) void k_fused(
    const float* __restrict__ rgb, const float* __restrict__ pos, const float* __restrict__ pos1,
    const float* __restrict__ pos2, const int* __restrict__ idx0, const int* __restrict__ idx1,
    const float* __restrict__ W1l, const float* __restrict__ b1l,
    const unsigned short* __restrict__ w1gT, const float* __restrict__ b1g,
    const unsigned short* __restrict__ w2lT, const float* __restrict__ b2l,
    const unsigned short* __restrict__ w2gT, const float* __restrict__ b2g,
    const unsigned short* __restrict__ w3lT, const float* __restrict__ b3l,
    unsigned short* __restrict__ aggws)
{
    const int g = blockIdx.x, t = threadIdx.x;
    const int lane = t & 63, wv = t >> 6;
    const int lr = lane & 15, quad = lane >> 4;

    __shared__ __align__(16) unsigned char smem[29184];
    uint2* const spts = (uint2*)smem;                              // [512]
    unsigned short* const aggT = (unsigned short*)(smem + 4096);   // [128][40]
    unsigned short* const xs16 = (unsigned short*)smem;            // [128][72]
    unsigned short* const HT   = (unsigned short*)smem;            // [64][136]
    unsigned short* const xs3  = (unsigned short*)smem;            // [32][168]
    unsigned short* const sT   = (unsigned short*)(smem + 18432);  // [32][136]
    unsigned short* const agg2 = (unsigned short*)(smem + 18432);  // [32][72]
    float* const red  = (float*)(smem + 18432);                    // [128][9]
    int* const cnt   = (int*)(smem + 27136);
    int* const start = (int*)(smem + 27648);
    int* const ctr   = (int*)(smem + 28160);
    unsigned short* const slc = (unsigned short*)(smem + 28672);
    int* const cnti  = (int*)(smem + 28928);
    float* const invc = (float*)(smem + 29056);

    // ---- pre-B0: counters, slc + rel regs, zero sT, zero aggT K-pad cols 16..31 ----
    if (t < CPG_) cnt[t] = 0;
    if (t < CPG2_) cnti[t] = 0;
    float relx = 0.f, rely = 0.f, relz = 0.f;
    if (t < CPG_) {
        const int c2 = idx1[g*CPG_ + t];
        slc[t] = (unsigned short)(c2 - g*CPG2_);
        relx = pos1[(g*CPG_ + t)*3 + 0] - pos2[c2*3 + 0];
        rely = pos1[(g*CPG_ + t)*3 + 1] - pos2[c2*3 + 1];
        relz = pos1[(g*CPG_ + t)*3 + 2] - pos2[c2*3 + 2];
    }
    for (int i = t; i < 2176; i += 256) ((unsigned*)sT)[i] = 0u;
    for (int i = t; i < 128*8; i += 256) {
        const int r = i >> 3, j = i & 7;
        ((unsigned*)aggT)[r*20 + 8 + j] = 0u;
    }
    __syncthreads();   // B0

    // ---- conv1 A: load 2 points to regs + count; one-hot scatter into sT ----
    if (t < CPG_) sT[slc[t]*136 + t] = 0x3F80;   // bf16 1.0
    float px0[2], prx[2], pry[2], prz[2];
    int plc[2];
    #pragma unroll
    for (int r = 0; r < 2; r++) {
        const int lp = r*256 + t;
        const int p  = g*NPG_ + lp;
        const int c  = idx0[p];
        plc[r] = c - g*CPG_;
        px0[r] = rgb[p];
        prx[r] = pos[p*3+0] - pos1[c*3+0];
        pry[r] = pos[p*3+1] - pos1[c*3+1];
        prz[r] = pos[p*3+2] - pos1[c*3+2];
        atomicAdd(&cnt[plc[r]], 1);
    }
    if (t < CPG_) atomicAdd(&cnti[slc[t]], 1);
    __syncthreads();   // B1

    // ---- scan (into ctr) ----
    if (t < CPG_) {
        int val = cnt[t];
        const int ln = t & 63;
        #pragma unroll
        for (int d = 1; d < 64; d <<= 1) {
            const int v = __shfl_up(val, d, 64);
            if (ln >= d) val += v;
        }
        ctr[t] = val;
    }
    __syncthreads();   // B2
    if (t < CPG_) {
        int v = ctr[t];
        if (t >= 64) v += ctr[63];
        const int s = v - cnt[t];
        start[t] = s; ctr[t] = s;
    }
    if (t < CPG2_) invc[t] = 1.f / fmaxf((float)cnti[t], 1.f);
    __syncthreads();   // B3

    // ---- C: scatter packed bf16 points into cluster-sorted AoS ----
    #pragma unroll
    for (int r = 0; r < 2; r++) {
        const int slot = atomicAdd(&ctr[plc[r]], 1);
        uint2 pk;
        pk.x = pack2(px0[r], prx[r]);
        pk.y = pack2(pry[r], prz[r]);
        spts[slot] = pk;
    }
    __syncthreads();   // B4

    // ---- D: accumulate per cluster (2 threads/cluster) -> aggT bf16 cols 0..15 ----
    {
        const int c = t >> 1, ch0 = (t & 1) * 8;
        float wj[8], wx[8], wy[8], wz[8], bb2[8];
        #pragma unroll
        for (int j = 0; j < 8; j++) {
            wj[j] = W1l[ch0+j]; wx[j] = W1l[16+ch0+j];
            wy[j] = W1l[32+ch0+j]; wz[j] = W1l[48+ch0+j];
            bb2[j] = b1l[ch0+j];
        }
        float a[8];
        #pragma unroll
        for (int j = 0; j < 8; j++) a[j] = 0.f;
        const int n = cnt[c], base = start[c];
        for (int i = 0; i < n; i++) {
            const uint2 pk = spts[base + i];
            const float x0 = bflo(pk.x), rx = bfhi(pk.x);
            const float ry = bflo(pk.y), rz = bfhi(pk.y);
            #pragma unroll
            for (int j = 0; j < 8; j++) {
                const float h = bb2[j] + x0*wj[j] + rx*wx[j] + ry*wy[j] + rz*wz[j];
                a[j] += celu_f(h);
            }
        }
        const float inv = 1.f / fmaxf((float)n, 1.f);
        uint2 q0, q1;
        q0.x = pack2(a[0]*inv, a[1]*inv);
        q0.y = pack2(a[2]*inv, a[3]*inv);
        q1.x = pack2(a[4]*inv, a[5]*inv);
        q1.y = pack2(a[6]*inv, a[7]*inv);
        *(uint2*)&aggT[c*40 + ch0]     = q0;
        *(uint2*)&aggT[c*40 + ch0 + 4] = q1;
    }
    __syncthreads();   // B5

    // ---- conv1 global conv MFMA: [128,32(K pad)] @ w1gT -> C regs ----
    f32x4 c1[2][2];    // [nt][mt]
    {
        #pragma unroll
        for (int nt = 0; nt < 2; nt++) {
            const float bias = b1g[nt*16 + lr];
            c1[nt][0] = (f32x4){bias, bias, bias, bias};
            c1[nt][1] = (f32x4){bias, bias, bias, bias};
        }
        const bf16x8 b0 = *(const bf16x8*)&w1gT[(0*16 + lr)*40 + quad*8];
        const bf16x8 b1 = *(const bf16x8*)&w1gT[(1*16 + lr)*40 + quad*8];
        #pragma unroll
        for (int mt = 0; mt < 2; mt++) {
            const bf16x8 a = *(const bf16x8*)&aggT[((2*wv + mt)*16 + lr)*40 + quad*8];
            c1[0][mt] = __builtin_amdgcn_mfma_f32_16x16x32_bf16(a, b0, c1[0][mt], 0, 0, 0);
            c1[1][mt] = __builtin_amdgcn_mfma_f32_16x16x32_bf16(a, b1, c1[1][mt], 0, 0, 0);
        }
    }
    __syncthreads();   // B6 (spts/aggT dead; Region1 -> xs16)

    // ---- write f1 into xs16 cols 0..31, relpos cols 32..34, zero 35..63 ----
    #pragma unroll
    for (int nt = 0; nt < 2; nt++)
    #pragma unroll
    for (int mt = 0; mt < 2; mt++)
    #pragma unroll
    for (int r = 0; r < 4; r++) {
        const int cl = (2*wv + mt)*16 + quad*4 + r;
        xs16[cl*72 + nt*16 + lr] = f2bf(celu_f(c1[nt][mt][r]));
    }
    if (t < CPG_) {
        xs16[t*72 + 32] = f2bf(relx);
        xs16[t*72 + 33] = f2bf(rely);
        xs16[t*72 + 34] = f2bf(relz);
    }
    for (int i = t; i < 128*29; i += 256) {
        const int r = i / 29, c = 35 + (i - r*29);
        xs16[r*72 + c] = 0;
    }
    __syncthreads();   // B7

    // ---- conv2 local MFMA ----
    float hv[8][4];
    {
        const int chn = wv*16 + lr;
        const bf16x8 bw0 = *(const bf16x8*)&w2lT[chn*64 + quad*8];
        const bf16x8 bw1 = *(const bf16x8*)&w2lT[chn*64 + 32 + quad*8];
        const float bias = b2l[chn];
        #pragma unroll
        for (int m = 0; m < 8; m++) {
            f32x4 acc = (f32x4){bias, bias, bias, bias};
            const bf16x8 a0 = *(const bf16x8*)&xs16[(m*16 + lr)*72 + quad*8];
            const bf16x8 a1 = *(const bf16x8*)&xs16[(m*16 + lr)*72 + 32 + quad*8];
            acc = __builtin_amdgcn_mfma_f32_16x16x32_bf16(a0, bw0, acc, 0, 0, 0);
            acc = __builtin_amdgcn_mfma_f32_16x16x32_bf16(a1, bw1, acc, 0, 0, 0);
            #pragma unroll
            for (int r = 0; r < 4; r++) hv[m][r] = celu_f(acc[r]);
        }
    }
    __syncthreads();   // B8 (xs16 dead -> HT)

    // ---- store H^T ----
    {
        const int chn = wv*16 + lr;
        #pragma unroll
        for (int m = 0; m < 8; m++) {
            uint2 p;
            p.x = pack2(hv[m][0], hv[m][1]);
            p.y = pack2(hv[m][2], hv[m][3]);
            *(uint2*)&HT[chn*136 + m*16 + quad*4] = p;
        }
    }
    __syncthreads();   // B9

    // ---- segment-sum MFMA agg[32][64] = S^T @ H ----
    float aggv[2][4];
    {
        const int ch = wv*16 + lr;
        f32x4 acc[2];
        acc[0] = (f32x4){0.f, 0.f, 0.f, 0.f};
        acc[1] = (f32x4){0.f, 0.f, 0.f, 0.f};
        #pragma unroll
        for (int ks = 0; ks < 4; ks++) {
            const bf16x8 b = *(const bf16x8*)&HT[ch*136 + ks*32 + quad*8];
            #pragma unroll
            for (int mt = 0; mt < 2; mt++) {
                const bf16x8 a = *(const bf16x8*)&sT[(mt*16 + lr)*136 + ks*32 + quad*8];
                acc[mt] = __builtin_amdgcn_mfma_f32_16x16x32_bf16(a, b, acc[mt], 0, 0, 0);
            }
        }
        #pragma unroll
        for (int mt = 0; mt < 2; mt++)
        #pragma unroll
        for (int r = 0; r < 4; r++)
            aggv[mt][r] = acc[mt][r] * invc[mt*16 + quad*4 + r];
    }
    __syncthreads();   // B10 (sT dead -> agg2; HT dead -> xs3)

    // ---- agg2 stores (Region2) + xs3 pads/zeros (Region1) ----
    {
        const int ch = wv*16 + lr;
        #pragma unroll
        for (int mt = 0; mt < 2; mt++)
        #pragma unroll
        for (int r = 0; r < 4; r++)
            agg2[(mt*16 + quad*4 + r)*72 + ch] = f2bf(aggv[mt][r]);
    }
    if (t < CPG2_) {
        #pragma unroll
        for (int d = 0; d < 3; d++)
            xs3[t*168 + 128 + d] = f2bf(pos2[(g*CPG2_ + t)*3 + d]);
    }
    for (int i = t; i < 32*29; i += 256) {
        const int r = i / 29, c = 131 + (i - r*29);
        xs3[r*168 + c] = 0;
    }
    __syncthreads();   // B11

    // ---- conv2 global MFMA -> f2 bf16 into xs3 cols 0..127 ----
    {
        f32x4 acc2[2][2];
        int   chn2[2];
        bf16x8 bw[2][2];
        #pragma unroll
        for (int nt = 0; nt < 2; nt++) {
            chn2[nt] = (wv + nt*4)*16 + lr;
            const float bias = b2g[chn2[nt]];
            #pragma unroll
            for (int mt = 0; mt < 2; mt++) acc2[nt][mt] = (f32x4){bias, bias, bias, bias};
            bw[nt][0] = *(const bf16x8*)&w2gT[chn2[nt]*64 + quad*8];
            bw[nt][1] = *(const bf16x8*)&w2gT[chn2[nt]*64 + 32 + quad*8];
        }
        #pragma unroll
        for (int ks = 0; ks < 2; ks++) {
            #pragma unroll
            for (int mt = 0; mt < 2; mt++) {
                const bf16x8 a = *(const bf16x8*)&agg2[(mt*16 + lr)*72 + ks*32 + quad*8];
                acc2[0][mt] = __builtin_amdgcn_mfma_f32_16x16x32_bf16(a, bw[0][ks], acc2[0][mt], 0, 0, 0);
                acc2[1][mt] = __builtin_amdgcn_mfma_f32_16x16x32_bf16(a, bw[1][ks], acc2[1][mt], 0, 0, 0);
            }
        }
        #pragma unroll
        for (int nt = 0; nt < 2; nt++)
        #pragma unroll
        for (int mt = 0; mt < 2; mt++)
        #pragma unroll
        for (int r = 0; r < 4; r++) {
            const int row = mt*16 + quad*4 + r;
            xs3[row*168 + chn2[nt]] = f2bf(celu_f(acc2[nt][mt][r]));
        }
    }
    __syncthreads();   // B12 (agg2 dead -> red)

    // ---- conv3 local MFMA (M=32) -> celu -> partials -> red ----
    {
        f32x4 acc[2][2];
        int chn[2];
        #pragma unroll
        for (int nt = 0; nt < 2; nt++) {
            chn[nt] = (wv + nt*4)*16 + lr;
            const float bias = b3l[chn[nt]];
            #pragma unroll
            for (int mt = 0; mt < 2; mt++) acc[nt][mt] = (f32x4){bias, bias, bias, bias};
        }
        #pragma unroll
        for (int ks = 0; ks < 5; ks++) {
            const bf16x8 b0 = *(const bf16x8*)&w3lT[chn[0]*160 + ks*32 + quad*8];
            const bf16x8 b1 = *(const bf16x8*)&w3lT[chn[1]*160 + ks*32 + quad*8];
            #pragma unroll
            for (int mt = 0; mt < 2; mt++) {
                const bf16x8 a = *(const bf16x8*)&xs3[(mt*16 + lr)*168 + ks*32 + quad*8];
                acc[0][mt] = __builtin_amdgcn_mfma_f32_16x16x32_bf16(a, b0, acc[0][mt], 0, 0, 0);
                acc[1][mt] = __builtin_amdgcn_mfma_f32_16x16x32_bf16(a, b1, acc[1][mt], 0, 0, 0);
            }
        }
        #pragma unroll
        for (int nt = 0; nt < 2; nt++)
        #pragma unroll
        for (int mt = 0; mt < 2; mt++) {
            const float p = celu_f(acc[nt][mt][0]) + celu_f(acc[nt][mt][1])
                          + celu_f(acc[nt][mt][2]) + celu_f(acc[nt][mt][3]);
            red[chn[nt]*9 + mt*4 + quad] = p;
        }
    }
    __syncthreads();   // B13

    // ---- mean -> aggws bf16 ----
    if (t < 128) {
        const float* rp = &red[t*9];
        float a = 0.f;
        #pragma unroll
        for (int p = 0; p < 8; p++) a += rp[p];
        aggws[(size_t)g*128 + t] = f2bf(a * (1.f/32.f));
    }
}

// ============== head: 16 glimpses per block; z/mu/sigma from paired accumulators ==============
__global__ __launch_bounds__(256) void k_head(
    const unsigned short* __restrict__ aggws,
    const unsigned short* __restrict__ w3gT, const float* __restrict__ b3g,
    const unsigned short* __restrict__ wlinT, const float* __restrict__ blin,
    const float* __restrict__ eps, float* __restrict__ out)
{
    const int g0 = blockIdx.x * 16, t = threadIdx.x;
    const int lane = t & 63, wv = t >> 6;
    const int lr = lane & 15, quad = lane >> 4;
    __shared__ __align__(16) unsigned short aggB[16*136];
    __shared__ __align__(16) unsigned short f3B[16*264];

    {   // stage agg rows: 256 uint4
        const int row = t >> 4, col8 = (t & 15) * 8;
        const uint4 v = ((const uint4*)aggws)[(size_t)g0*16 + t];
        *(uint4*)&aggB[row*136 + col8] = v;
    }
    __syncthreads();

    // W3g MFMA: C[16 glimpses][256] = aggB @ W3g
    {
        f32x4 c3[4];
        int ch3[4];
        #pragma unroll
        for (int nt = 0; nt < 4; nt++) {
            ch3[nt] = (wv + nt*4)*16 + lr;
            const float bias = b3g[ch3[nt]];
            c3[nt] = (f32x4){bias, bias, bias, bias};
        }
        #pragma unroll
        for (int ks = 0; ks < 4; ks++) {
            const bf16x8 a = *(const bf16x8*)&aggB[lr*136 + ks*32 + quad*8];
            #pragma unroll
            for (int nt = 0; nt < 4; nt++) {
                const bf16x8 b = *(const bf16x8*)&w3gT[ch3[nt]*128 + ks*32 + quad*8];
                c3[nt] = __builtin_amdgcn_mfma_f32_16x16x32_bf16(a, b, c3[nt], 0, 0, 0);
            }
        }
        #pragma unroll
        for (int nt = 0; nt < 4; nt++)
        #pragma unroll
        for (int r = 0; r < 4; r++) {
            const int row = quad*4 + r;
            const float v = celu_f(c3[nt][r]);
            out[OFF_F + (size_t)(g0 + row)*256 + ch3[nt]] = v;
            f3B[row*264 + ch3[nt]] = f2bf(v);
        }
    }
    __syncthreads();

    // Wlin MFMA: C[16][256] = f3B @ Wlin; sample in-register (lane owns ch and ch+128)
    {
        f32x4 cl[4];
        int ch4[4];
        #pragma unroll
        for (int nt = 0; nt < 4; nt++) {
            ch4[nt] = (wv + nt*4)*16 + lr;
            const float bias = blin[ch4[nt]];
            cl[nt] = (f32x4){bias, bias, bias, bias};
        }
        #pragma unroll
        for (int ks = 0; ks < 8; ks++) {
            const bf16x8 a = *(const bf16x8*)&f3B[lr*264 + ks*32 + quad*8];
            #pragma unroll
            for (int nt = 0; nt < 4; nt++) {
                const bf16x8 b = *(const bf16x8*)&wlinT[ch4[nt]*256 + ks*32 + quad*8];
                cl[nt] = __builtin_amdgcn_mfma_f32_16x16x32_bf16(a, b, cl[nt], 0, 0, 0);
            }
        }
        // nt and nt+2 share the lane: ch4[nt+2] == ch4[nt] + 128
        #pragma unroll
        for (int nt = 0; nt < 2; nt++)
        #pragma unroll
        for (int r = 0; r < 4; r++) {
            const int row = quad*4 + r;
            const int g = g0 + row;
            const int ch = ch4[nt];                 // 0..127
            const float mu    = cl[nt][r];
            const float sigma = softplus_f(cl[nt + 2][r]);
            const float z     = mu + sigma * eps[(size_t)g*128 + ch];
            out[OFF_MU + (size_t)g*128 + ch] = mu;
            out[OFF_SG + (size_t)g*128 + ch] = sigma;
            if (nt == 0) out[OFF_ZW + (size_t)g*64 + ch] = z;          // ch in [0,64)
            else         out[OFF_ZM + (size_t)g*64 + (ch - 64)] = z;   // ch in [64,128)
        }
    }
}

extern "C" void kernel_launch(void* const* d_in, const int* in_sizes, int n_in,
                              void* d_out, int out_size, void* d_ws, size_t ws_size,
                              hipStream_t stream)
{
    const float* rgb  = (const float*)d_in[0];
    const float* pos  = (const float*)d_in[1];
    const float* pos1 = (const float*)d_in[2];
    const float* pos2 = (const float*)d_in[3];
    const int*   idx0 = (const int*)d_in[4];
    const int*   idx1 = (const int*)d_in[5];
    const float* eps  = (const float*)d_in[7];
    const float* W1l = (const float*)d_in[8],  *b1l = (const float*)d_in[9];
    const float* W1g = (const float*)d_in[10], *b1g = (const float*)d_in[11];
    const float* W2l = (const float*)d_in[12], *b2l = (const float*)d_in[13];
    const float* W2g = (const float*)d_in[14], *b2g = (const float*)d_in[15];
    const float* W3l = (const float*)d_in[16], *b3l = (const float*)d_in[17];
    const float* W3g = (const float*)d_in[18], *b3g = (const float*)d_in[19];
    const float* Wlin = (const float*)d_in[20], *blin = (const float*)d_in[21];

    unsigned short* w2lT  = (unsigned short*)d_ws;       // 64*64
    unsigned short* w2gT  = w2lT + 64*64;                // 128*64
    unsigned short* w3lT  = w2gT + 128*64;               // 128*160
    unsigned short* w3gT  = w3lT + 128*160;              // 256*128
    unsigned short* wlinT = w3gT + 256*128;              // 256*256
    unsigned short* w1gT  = wlinT + 256*256;             // 32*40
    unsigned short* aggws = w1gT + 32*40;                // G*128 bf16
    float* outp = (float*)d_out;

    k_prep <<<64,    256, 0, stream>>>(W2l, W2g, W3l, W3g, Wlin, W1g,
                                       w2lT, w2gT, w3lT, w3gT, wlinT, w1gT);
    k_fused<<<G_,    256, 0, stream>>>(rgb, pos, pos1, pos2, idx0, idx1,
                                       W1l, b1l, w1gT, b1g,
                                       w2lT, b2l, w2gT, b2g, w3lT, b3l, aggws);
    k_head <<<G_/16, 256, 0, stream>>>(aggws, w3gT, b3g, wlinT, blin, eps, outp);
}

// Round 15
// 155.552 us; speedup vs baseline: 1.2692x; 1.0131x over previous
//
#include <hip/hip_runtime.h>
#include <hip/hip_bf16.h>
#include <cstddef>

#define G_   2048
#define NPG_ 512
#define CPG_ 128
#define CPG2_ 32

// output layout (floats): z_what[G,64] | z_mask[G,64] | mu[G,128] | sigma[G,128] | f[G,256]
#define OFF_ZW 0
#define OFF_ZM (G_*64)
#define OFF_MU (2*G_*64)
#define OFF_SG (2*G_*64 + G_*128)
#define OFF_F  (2*G_*64 + 2*G_*128)

typedef __attribute__((ext_vector_type(8))) short bf16x8;
typedef __attribute__((ext_vector_type(4))) float f32x4;

__device__ __forceinline__ float celu_f(float x)     { return x > 0.f ? x : __expf(x) - 1.f; }
__device__ __forceinline__ float softplus_f(float x) { return fmaxf(x, 0.f) + __logf(1.f + __expf(-fabsf(x))); }
// fast RNE fp32->bf16 (finite inputs): identical result to __float2bfloat16
__device__ __forceinline__ unsigned short f2bf(float x) {
    unsigned u = __float_as_uint(x);
    u += 0x7FFFu + ((u >> 16) & 1u);
    return (unsigned short)(u >> 16);
}
__device__ __forceinline__ unsigned pack2(float a, float b) {   // bf16(a) | bf16(b)<<16
    unsigned ua = __float_as_uint(a); ua += 0x7FFFu + ((ua >> 16) & 1u);
    unsigned ub = __float_as_uint(b); ub += 0x7FFFu + ((ub >> 16) & 1u);
    return (ua >> 16) | (ub & 0xFFFF0000u);
}
__device__ __forceinline__ float bflo(unsigned w) { return __uint_as_float(w << 16); }
__device__ __forceinline__ float bfhi(unsigned w) { return __uint_as_float(w & 0xffff0000u); }
// 8B-aligned bf16x8 LDS load (for stride-132 rows)
__device__ __forceinline__ bf16x8 ldb8(const unsigned short* p) {
    union { uint2 u[2]; bf16x8 v; } x;
    x.u[0] = *(const uint2*)p;
    x.u[1] = *(const uint2*)(p + 4);
    return x.v;
}

// ---------------- prep: transposed, zero-K-padded bf16 weight copies in ws ----------------
__global__ void k_prep(const float* __restrict__ W2l, const float* __restrict__ W2g,
                       const float* __restrict__ W3l, const float* __restrict__ W3g,
                       const float* __restrict__ Wlin, const float* __restrict__ W1g,
                       unsigned short* __restrict__ w2lT, unsigned short* __restrict__ w2gT,
                       unsigned short* __restrict__ w3lT, unsigned short* __restrict__ w3gT,
                       unsigned short* __restrict__ wlinT, unsigned short* __restrict__ w1gT)
{
    const int tid = blockIdx.x*256 + threadIdx.x, stride = gridDim.x*256;
    for (int i = tid; i < 64*64; i += stride) {          // W2l [35,64] -> [ch][k=64pad]
        const int ch = i >> 6, k = i & 63;
        w2lT[i] = f2bf(k < 35 ? W2l[k*64 + ch] : 0.f);
    }
    for (int i = tid; i < 128*64; i += stride) {         // W2g [64,128] -> [ch][k]
        const int ch = i >> 6, k = i & 63;
        w2gT[i] = f2bf(W2g[k*128 + ch]);
    }
    for (int i = tid; i < 128*160; i += stride) {        // W3l [131,128] -> [ch][k=160pad]
        const int ch = i / 160, k = i % 160;
        w3lT[i] = f2bf(k < 131 ? W3l[k*128 + ch] : 0.f);
    }
    for (int i = tid; i < 256*128; i += stride) {        // W3g [128,256] -> [ch][k]
        const int ch = i >> 7, k = i & 127;
        w3gT[i] = f2bf(W3g[k*256 + ch]);
    }
    for (int i = tid; i < 256*256; i += stride) {        // Wlin [256,256] -> [ch][k]
        const int ch = i >> 8, k = i & 255;
        wlinT[i] = f2bf(Wlin[k*256 + ch]);
    }
    for (int i = tid; i < 32*40; i += stride) {          // W1g [16,32] -> [ch][k=40pad]
        const int ch = i / 40, k = i % 40;
        w1gT[i] = f2bf(k < 16 ? W1g[k*32 + ch] : 0.f);
    }
}

// ============== fused conv1+conv2+conv3local+mean: one block per glimpse ==============
// LDS 27008 B (rounds to 27136 -> 6 blocks/CU), phase overlays:
//  Region1 [0,18432):   spts u2[512] @0 + aggT us[128][40] @4096 (conv1)
//                       -> xs16 us[128][72] -> HT us[64][136] -> xs3 us[32][168]
//  Region2 [18432,26880): cnt/start/ctr int[128]x3 + cnti int[32] (conv1, dead by B6)
//                       -> sT us[32][132] -> agg2 us[32][72] -> red f32[128][9]
//  invc f32[32] @26880
__global__ __launch_bounds__(256, 6) void k_fused(
    const float* __restrict__ rgb, const float* __restrict__ pos, const float* __restrict__ pos1,
    const float* __restrict__ pos2, const int* __restrict__ idx0, const int* __restrict__ idx1,
    const float* __restrict__ W1l, const float* __restrict__ b1l,
    const unsigned short* __restrict__ w1gT, const float* __restrict__ b1g,
    const unsigned short* __restrict__ w2lT, const float* __restrict__ b2l,
    const unsigned short* __restrict__ w2gT, const float* __restrict__ b2g,
    const unsigned short* __restrict__ w3lT, const float* __restrict__ b3l,
    unsigned short* __restrict__ aggws)
{
    const int g = blockIdx.x, t = threadIdx.x;
    const int lane = t & 63, wv = t >> 6;
    const int lr = lane & 15, quad = lane >> 4;

    __shared__ __align__(16) unsigned char smem[27008];
    uint2* const spts = (uint2*)smem;                              // [512]
    unsigned short* const aggT = (unsigned short*)(smem + 4096);   // [128][40]
    unsigned short* const xs16 = (unsigned short*)smem;            // [128][72]
    unsigned short* const HT   = (unsigned short*)smem;            // [64][136]
    unsigned short* const xs3  = (unsigned short*)smem;            // [32][168]
    int* const cnt   = (int*)(smem + 18432);
    int* const start = (int*)(smem + 18944);
    int* const ctr   = (int*)(smem + 19456);
    int* const cnti  = (int*)(smem + 19968);
    unsigned short* const sT   = (unsigned short*)(smem + 18432);  // [32][132]
    unsigned short* const agg2 = (unsigned short*)(smem + 18432);  // [32][72]
    float* const red  = (float*)(smem + 18432);                    // [128][9]
    float* const invc = (float*)(smem + 26880);                    // [32]

    // ---- pre-B0: counters, slc/rel into regs, zero aggT K-pad cols 16..31 ----
    if (t < CPG_) cnt[t] = 0;
    if (t < CPG2_) cnti[t] = 0;
    int slc_r = 0;
    float relx = 0.f, rely = 0.f, relz = 0.f;
    if (t < CPG_) {
        const int c2 = idx1[g*CPG_ + t];
        slc_r = c2 - g*CPG2_;
        relx = pos1[(g*CPG_ + t)*3 + 0] - pos2[c2*3 + 0];
        rely = pos1[(g*CPG_ + t)*3 + 1] - pos2[c2*3 + 1];
        relz = pos1[(g*CPG_ + t)*3 + 2] - pos2[c2*3 + 2];
    }
    for (int i = t; i < 128*8; i += 256) {
        const int r = i >> 3, j = i & 7;
        ((unsigned*)aggT)[r*20 + 8 + j] = 0u;
    }
    __syncthreads();   // B0

    // ---- conv1 A: load 2 points to regs + counts ----
    float px0[2], prx[2], pry[2], prz[2];
    int plc[2];
    #pragma unroll
    for (int r = 0; r < 2; r++) {
        const int lp = r*256 + t;
        const int p  = g*NPG_ + lp;
        const int c  = idx0[p];
        plc[r] = c - g*CPG_;
        px0[r] = rgb[p];
        prx[r] = pos[p*3+0] - pos1[c*3+0];
        pry[r] = pos[p*3+1] - pos1[c*3+1];
        prz[r] = pos[p*3+2] - pos1[c*3+2];
        atomicAdd(&cnt[plc[r]], 1);
    }
    if (t < CPG_) atomicAdd(&cnti[slc_r], 1);
    __syncthreads();   // B1

    // ---- scan (into ctr) ----
    if (t < CPG_) {
        int val = cnt[t];
        const int ln = t & 63;
        #pragma unroll
        for (int d = 1; d < 64; d <<= 1) {
            const int v = __shfl_up(val, d, 64);
            if (ln >= d) val += v;
        }
        ctr[t] = val;
    }
    __syncthreads();   // B2
    if (t < CPG_) {
        int v = ctr[t];
        if (t >= 64) v += ctr[63];
        const int s = v - cnt[t];
        start[t] = s; ctr[t] = s;
    }
    if (t < CPG2_) invc[t] = 1.f / fmaxf((float)cnti[t], 1.f);
    __syncthreads();   // B3

    // ---- C: scatter packed bf16 points into cluster-sorted AoS ----
    #pragma unroll
    for (int r = 0; r < 2; r++) {
        const int slot = atomicAdd(&ctr[plc[r]], 1);
        uint2 pk;
        pk.x = pack2(px0[r], prx[r]);
        pk.y = pack2(pry[r], prz[r]);
        spts[slot] = pk;
    }
    __syncthreads();   // B4

    // ---- D: accumulate per cluster (2 threads/cluster) -> aggT bf16 cols 0..15 ----
    {
        const int c = t >> 1, ch0 = (t & 1) * 8;
        float wj[8], wx[8], wy[8], wz[8], bb2[8];
        #pragma unroll
        for (int j = 0; j < 8; j++) {
            wj[j] = W1l[ch0+j]; wx[j] = W1l[16+ch0+j];
            wy[j] = W1l[32+ch0+j]; wz[j] = W1l[48+ch0+j];
            bb2[j] = b1l[ch0+j];
        }
        float a[8];
        #pragma unroll
        for (int j = 0; j < 8; j++) a[j] = 0.f;
        const int n = cnt[c], base = start[c];
        for (int i = 0; i < n; i++) {
            const uint2 pk = spts[base + i];
            const float x0 = bflo(pk.x), rx = bfhi(pk.x);
            const float ry = bflo(pk.y), rz = bfhi(pk.y);
            #pragma unroll
            for (int j = 0; j < 8; j++) {
                const float h = bb2[j] + x0*wj[j] + rx*wx[j] + ry*wy[j] + rz*wz[j];
                a[j] += celu_f(h);
            }
        }
        const float inv = 1.f / fmaxf((float)n, 1.f);
        uint2 q0, q1;
        q0.x = pack2(a[0]*inv, a[1]*inv);
        q0.y = pack2(a[2]*inv, a[3]*inv);
        q1.x = pack2(a[4]*inv, a[5]*inv);
        q1.y = pack2(a[6]*inv, a[7]*inv);
        *(uint2*)&aggT[c*40 + ch0]     = q0;
        *(uint2*)&aggT[c*40 + ch0 + 4] = q1;
    }
    __syncthreads();   // B5

    // ---- conv1 global conv MFMA: [128,32(K pad)] @ w1gT -> C regs ----
    f32x4 c1[2][2];    // [nt][mt]
    {
        #pragma unroll
        for (int nt = 0; nt < 2; nt++) {
            const float bias = b1g[nt*16 + lr];
            c1[nt][0] = (f32x4){bias, bias, bias, bias};
            c1[nt][1] = (f32x4){bias, bias, bias, bias};
        }
        const bf16x8 b0 = *(const bf16x8*)&w1gT[(0*16 + lr)*40 + quad*8];
        const bf16x8 b1 = *(const bf16x8*)&w1gT[(1*16 + lr)*40 + quad*8];
        #pragma unroll
        for (int mt = 0; mt < 2; mt++) {
            const bf16x8 a = *(const bf16x8*)&aggT[((2*wv + mt)*16 + lr)*40 + quad*8];
            c1[0][mt] = __builtin_amdgcn_mfma_f32_16x16x32_bf16(a, b0, c1[0][mt], 0, 0, 0);
            c1[1][mt] = __builtin_amdgcn_mfma_f32_16x16x32_bf16(a, b1, c1[1][mt], 0, 0, 0);
        }
    }
    __syncthreads();   // B6 (spts/aggT dead -> xs16; cnt/start/ctr/cnti dead -> sT)

    // ---- zero sT; write f1 into xs16 cols 0..31, relpos 32..34, zero 35..63 ----
    {
        const uint4 z4 = {0u, 0u, 0u, 0u};
        for (int i = t; i < 528; i += 256) ((uint4*)sT)[i] = z4;   // 32*132 us = 8448 B
    }
    #pragma unroll
    for (int nt = 0; nt < 2; nt++)
    #pragma unroll
    for (int mt = 0; mt < 2; mt++)
    #pragma unroll
    for (int r = 0; r < 4; r++) {
        const int cl = (2*wv + mt)*16 + quad*4 + r;
        xs16[cl*72 + nt*16 + lr] = f2bf(celu_f(c1[nt][mt][r]));
    }
    if (t < CPG_) {
        xs16[t*72 + 32] = f2bf(relx);
        xs16[t*72 + 33] = f2bf(rely);
        xs16[t*72 + 34] = f2bf(relz);
    }
    for (int i = t; i < 128*29; i += 256) {
        const int r = i / 29, c = 35 + (i - r*29);
        xs16[r*72 + c] = 0;
    }
    __syncthreads();   // B7

    // ---- one-hot scatter into sT; conv2 local MFMA (reads xs16) ----
    if (t < CPG_) sT[slc_r*132 + t] = 0x3F80;   // bf16 1.0
    float hv[8][4];
    {
        const int chn = wv*16 + lr;
        const bf16x8 bw0 = *(const bf16x8*)&w2lT[chn*64 + quad*8];
        const bf16x8 bw1 = *(const bf16x8*)&w2lT[chn*64 + 32 + quad*8];
        const float bias = b2l[chn];
        #pragma unroll
        for (int m = 0; m < 8; m++) {
            f32x4 acc = (f32x4){bias, bias, bias, bias};
            const bf16x8 a0 = *(const bf16x8*)&xs16[(m*16 + lr)*72 + quad*8];
            const bf16x8 a1 = *(const bf16x8*)&xs16[(m*16 + lr)*72 + 32 + quad*8];
            acc = __builtin_amdgcn_mfma_f32_16x16x32_bf16(a0, bw0, acc, 0, 0, 0);
            acc = __builtin_amdgcn_mfma_f32_16x16x32_bf16(a1, bw1, acc, 0, 0, 0);
            #pragma unroll
            for (int r = 0; r < 4; r++) hv[m][r] = celu_f(acc[r]);
        }
    }
    __syncthreads();   // B8 (xs16 dead -> HT)

    // ---- store H^T ----
    {
        const int chn = wv*16 + lr;
        #pragma unroll
        for (int m = 0; m < 8; m++) {
            uint2 p;
            p.x = pack2(hv[m][0], hv[m][1]);
            p.y = pack2(hv[m][2], hv[m][3]);
            *(uint2*)&HT[chn*136 + m*16 + quad*4] = p;
        }
    }
    __syncthreads();   // B9

    // ---- segment-sum MFMA agg[32][64] = S^T @ H (sT rows 8B-aligned -> ldb8) ----
    float aggv[2][4];
    {
        const int ch = wv*16 + lr;
        f32x4 acc[2];
        acc[0] = (f32x4){0.f, 0.f, 0.f, 0.f};
        acc[1] = (f32x4){0.f, 0.f, 0.f, 0.f};
        #pragma unroll
        for (int ks = 0; ks < 4; ks++) {
            const bf16x8 b = *(const bf16x8*)&HT[ch*136 + ks*32 + quad*8];
            #pragma unroll
            for (int mt = 0; mt < 2; mt++) {
                const bf16x8 a = ldb8(&sT[(mt*16 + lr)*132 + ks*32 + quad*8]);
                acc[mt] = __builtin_amdgcn_mfma_f32_16x16x32_bf16(a, b, acc[mt], 0, 0, 0);
            }
        }
        #pragma unroll
        for (int mt = 0; mt < 2; mt++)
        #pragma unroll
        for (int r = 0; r < 4; r++)
            aggv[mt][r] = acc[mt][r] * invc[mt*16 + quad*4 + r];
    }
    __syncthreads();   // B10 (sT dead -> agg2; HT dead -> xs3)

    // ---- agg2 stores (Region2) + xs3 pads/zeros (Region1) ----
    {
        const int ch = wv*16 + lr;
        #pragma unroll
        for (int mt = 0; mt < 2; mt++)
        #pragma unroll
        for (int r = 0; r < 4; r++)
            agg2[(mt*16 + quad*4 + r)*72 + ch] = f2bf(aggv[mt][r]);
    }
    if (t < CPG2_) {
        #pragma unroll
        for (int d = 0; d < 3; d++)
            xs3[t*168 + 128 + d] = f2bf(pos2[(g*CPG2_ + t)*3 + d]);
    }
    for (int i = t; i < 32*29; i += 256) {
        const int r = i / 29, c = 131 + (i - r*29);
        xs3[r*168 + c] = 0;
    }
    __syncthreads();   // B11

    // ---- conv2 global MFMA -> f2 bf16 into xs3 cols 0..127 ----
    {
        f32x4 acc2[2][2];
        int   chn2[2];
        bf16x8 bw[2][2];
        #pragma unroll
        for (int nt = 0; nt < 2; nt++) {
            chn2[nt] = (wv + nt*4)*16 + lr;
            const float bias = b2g[chn2[nt]];
            #pragma unroll
            for (int mt = 0; mt < 2; mt++) acc2[nt][mt] = (f32x4){bias, bias, bias, bias};
            bw[nt][0] = *(const bf16x8*)&w2gT[chn2[nt]*64 + quad*8];
            bw[nt][1] = *(const bf16x8*)&w2gT[chn2[nt]*64 + 32 + quad*8];
        }
        #pragma unroll
        for (int ks = 0; ks < 2; ks++) {
            #pragma unroll
            for (int mt = 0; mt < 2; mt++) {
                const bf16x8 a = *(const bf16x8*)&agg2[(mt*16 + lr)*72 + ks*32 + quad*8];
                acc2[0][mt] = __builtin_amdgcn_mfma_f32_16x16x32_bf16(a, bw[0][ks], acc2[0][mt], 0, 0, 0);
                acc2[1][mt] = __builtin_amdgcn_mfma_f32_16x16x32_bf16(a, bw[1][ks], acc2[1][mt], 0, 0, 0);
            }
        }
        #pragma unroll
        for (int nt = 0; nt < 2; nt++)
        #pragma unroll
        for (int mt = 0; mt < 2; mt++)
        #pragma unroll
        for (int r = 0; r < 4; r++) {
            const int row = mt*16 + quad*4 + r;
            xs3[row*168 + chn2[nt]] = f2bf(celu_f(acc2[nt][mt][r]));
        }
    }
    __syncthreads();   // B12 (agg2 dead -> red)

    // ---- conv3 local MFMA (M=32) -> celu -> partials -> red ----
    {
        f32x4 acc[2][2];
        int chn[2];
        #pragma unroll
        for (int nt = 0; nt < 2; nt++) {
            chn[nt] = (wv + nt*4)*16 + lr;
            const float bias = b3l[chn[nt]];
            #pragma unroll
            for (int mt = 0; mt < 2; mt++) acc[nt][mt] = (f32x4){bias, bias, bias, bias};
        }
        #pragma unroll
        for (int ks = 0; ks < 5; ks++) {
            const bf16x8 b0 = *(const bf16x8*)&w3lT[chn[0]*160 + ks*32 + quad*8];
            const bf16x8 b1 = *(const bf16x8*)&w3lT[chn[1]*160 + ks*32 + quad*8];
            #pragma unroll
            for (int mt = 0; mt < 2; mt++) {
                const bf16x8 a = *(const bf16x8*)&xs3[(mt*16 + lr)*168 + ks*32 + quad*8];
                acc[0][mt] = __builtin_amdgcn_mfma_f32_16x16x32_bf16(a, b0, acc[0][mt], 0, 0, 0);
                acc[1][mt] = __builtin_amdgcn_mfma_f32_16x16x32_bf16(a, b1, acc[1][mt], 0, 0, 0);
            }
        }
        #pragma unroll
        for (int nt = 0; nt < 2; nt++)
        #pragma unroll
        for (int mt = 0; mt < 2; mt++) {
            const float p = celu_f(acc[nt][mt][0]) + celu_f(acc[nt][mt][1])
                          + celu_f(acc[nt][mt][2]) + celu_f(acc[nt][mt][3]);
            red[chn[nt]*9 + mt*4 + quad] = p;
        }
    }
    __syncthreads();   // B13

    // ---- mean -> aggws bf16 ----
    if (t < 128) {
        const float* rp = &red[t*9];
        float a = 0.f;
        #pragma unroll
        for (int p = 0; p < 8; p++) a += rp[p];
        aggws[(size_t)g*128 + t] = f2bf(a * (1.f/32.f));
    }
}

// ============== head: 16 glimpses per block; z/mu/sigma from paired accumulators ==============
__global__ __launch_bounds__(256) void k_head(
    const unsigned short* __restrict__ aggws,
    const unsigned short* __restrict__ w3gT, const float* __restrict__ b3g,
    const unsigned short* __restrict__ wlinT, const float* __restrict__ blin,
    const float* __restrict__ eps, float* __restrict__ out)
{
    const int g0 = blockIdx.x * 16, t = threadIdx.x;
    const int lane = t & 63, wv = t >> 6;
    const int lr = lane & 15, quad = lane >> 4;
    __shared__ __align__(16) unsigned short aggB[16*136];
    __shared__ __align__(16) unsigned short f3B[16*264];

    {   // stage agg rows: 256 uint4
        const int row = t >> 4, col8 = (t & 15) * 8;
        const uint4 v = ((const uint4*)aggws)[(size_t)g0*16 + t];
        *(uint4*)&aggB[row*136 + col8] = v;
    }
    __syncthreads();

    // W3g MFMA: C[16 glimpses][256] = aggB @ W3g
    {
        f32x4 c3[4];
        int ch3[4];
        #pragma unroll
        for (int nt = 0; nt < 4; nt++) {
            ch3[nt] = (wv + nt*4)*16 + lr;
            const float bias = b3g[ch3[nt]];
            c3[nt] = (f32x4){bias, bias, bias, bias};
        }
        #pragma unroll
        for (int ks = 0; ks < 4; ks++) {
            const bf16x8 a = *(const bf16x8*)&aggB[lr*136 + ks*32 + quad*8];
            #pragma unroll
            for (int nt = 0; nt < 4; nt++) {
                const bf16x8 b = *(const bf16x8*)&w3gT[ch3[nt]*128 + ks*32 + quad*8];
                c3[nt] = __builtin_amdgcn_mfma_f32_16x16x32_bf16(a, b, c3[nt], 0, 0, 0);
            }
        }
        #pragma unroll
        for (int nt = 0; nt < 4; nt++)
        #pragma unroll
        for (int r = 0; r < 4; r++) {
            const int row = quad*4 + r;
            const float v = celu_f(c3[nt][r]);
            out[OFF_F + (size_t)(g0 + row)*256 + ch3[nt]] = v;
            f3B[row*264 + ch3[nt]] = f2bf(v);
        }
    }
    __syncthreads();

    // Wlin MFMA: C[16][256] = f3B @ Wlin; sample in-register (lane owns ch and ch+128)
    {
        f32x4 cl[4];
        int ch4[4];
        #pragma unroll
        for (int nt = 0; nt < 4; nt++) {
            ch4[nt] = (wv + nt*4)*16 + lr;
            const float bias = blin[ch4[nt]];
            cl[nt] = (f32x4){bias, bias, bias, bias};
        }
        #pragma unroll
        for (int ks = 0; ks < 8; ks++) {
            const bf16x8 a = *(const bf16x8*)&f3B[lr*264 + ks*32 + quad*8];
            #pragma unroll
            for (int nt = 0; nt < 4; nt++) {
                const bf16x8 b = *(const bf16x8*)&wlinT[ch4[nt]*256 + ks*32 + quad*8];
                cl[nt] = __builtin_amdgcn_mfma_f32_16x16x32_bf16(a, b, cl[nt], 0, 0, 0);
            }
        }
        // nt and nt+2 share the lane: ch4[nt+2] == ch4[nt] + 128
        #pragma unroll
        for (int nt = 0; nt < 2; nt++)
        #pragma unroll
        for (int r = 0; r < 4; r++) {
            const int row = quad*4 + r;
            const int g = g0 + row;
            const int ch = ch4[nt];                 // 0..127
            const float mu    = cl[nt][r];
            const float sigma = softplus_f(cl[nt + 2][r]);
            const float z     = mu + sigma * eps[(size_t)g*128 + ch];
            out[OFF_MU + (size_t)g*128 + ch] = mu;
            out[OFF_SG + (size_t)g*128 + ch] = sigma;
            if (nt == 0) out[OFF_ZW + (size_t)g*64 + ch] = z;          // ch in [0,64)
            else         out[OFF_ZM + (size_t)g*64 + (ch - 64)] = z;   // ch in [64,128)
        }
    }
}

extern "C" void kernel_launch(void* const* d_in, const int* in_sizes, int n_in,
                              void* d_out, int out_size, void* d_ws, size_t ws_size,
                              hipStream_t stream)
{
    const float* rgb  = (const float*)d_in[0];
    const float* pos  = (const float*)d_in[1];
    const float* pos1 = (const float*)d_in[2];
    const float* pos2 = (const float*)d_in[3];
    const int*   idx0 = (const int*)d_in[4];
    const int*   idx1 = (const int*)d_in[5];
    const float* eps  = (const float*)d_in[7];
    const float* W1l = (const float*)d_in[8],  *b1l = (const float*)d_in[9];
    const float* W1g = (const float*)d_in[10], *b1g = (const float*)d_in[11];
    const float* W2l = (const float*)d_in[12], *b2l = (const float*)d_in[13];
    const float* W2g = (const float*)d_in[14], *b2g = (const float*)d_in[15];
    const float* W3l = (const float*)d_in[16], *b3l = (const float*)d_in[17];
    const float* W3g = (const float*)d_in[18], *b3g = (const float*)d_in[19];
    const float* Wlin = (const float*)d_in[20], *blin = (const float*)d_in[21];

    unsigned short* w2lT  = (unsigned short*)d_ws;       // 64*64
    unsigned short* w2gT  = w2lT + 64*64;                // 128*64
    unsigned short* w3lT  = w2gT + 128*64;               // 128*160
    unsigned short* w3gT  = w3lT + 128*160;              // 256*128
    unsigned short* wlinT = w3gT + 256*128;              // 256*256
    unsigned short* w1gT  = wlinT + 256*256;             // 32*40
    unsigned short* aggws = w1gT + 32*40;                // G*128 bf16
    float* outp = (float*)d_out;

    k_prep <<<64,    256, 0, stream>>>(W2l, W2g, W3l, W3g, Wlin, W1g,
                                       w2lT, w2gT, w3lT, w3gT, wlinT, w1gT);
    k_fused<<<G_,    256, 0, stream>>>(rgb, pos, pos1, pos2, idx0, idx1,
                                       W1l, b1l, w1gT, b1g,
                                       w2lT, b2l, w2gT, b2g, w3lT, b3l, aggws);
    k_head <<<G_/16, 256, 0, stream>>>(aggws, w3gT, b3g, wlinT, blin, eps, outp);
}